// Round 1
// baseline (1750.642 us; speedup 1.0000x reference)
//
#include <hip/hip_runtime.h>
#include <cstdint>

#define N_ 16
#define C_ 256
#define H_ 64
#define W_ 64
#define L_ 4096          // H*W
#define K_ 32
#define CL_ (C_*L_)      // 1048576
#define KL_ (K_*L_)      // 131072
#define KC_ (K_*C_)      // 8192

// ---------- K1: per-pixel 1/max(||x||,eps) ----------
__global__ __launch_bounds__(256) void k_rinv(const float* __restrict__ f, float* __restrict__ rinv) {
    int p = blockIdx.x * 256 + threadIdx.x;          // 0..65535
    int n = p >> 12, l = p & (L_ - 1);
    const float* fp = f + (size_t)n * CL_ + l;
    float s = 0.f;
#pragma unroll 8
    for (int c = 0; c < C_; ++c) { float v = fp[(size_t)c * L_]; s = fmaf(v, v, s); }
    rinv[p] = 1.0f / fmaxf(sqrtf(s), 1e-12f);
}

// ---------- K2: 3x3 conv (on normalized feature) + bias + softmax over K ----------
__global__ __launch_bounds__(128) void k_conv_softmax(
    const float* __restrict__ f, const float* __restrict__ rinv,
    const float* __restrict__ w, const float* __restrict__ b,
    float* __restrict__ sa)
{
    int bid = blockIdx.x;                       // 512
    int n = bid >> 5;
    int y = ((bid & 31) << 1) + (threadIdx.x >> 6);
    int x = threadIdx.x & 63;
    int l = (y << 6) + x;
    const float* fp = f + (size_t)n * CL_;
    const float* rp = rinv + n * L_;
    int off[9]; float rv[9];
#pragma unroll
    for (int t = 0; t < 9; ++t) {
        int dy = t / 3 - 1, dx = t % 3 - 1;
        int yy = y + dy, xx = x + dx;
        bool ok = (yy >= 0 && yy < H_ && xx >= 0 && xx < W_);
        int o = (ok ? yy : y) * W_ + (ok ? xx : x);
        off[t] = o;
        rv[t] = ok ? rp[o] : 0.f;               // invalid taps contribute 0 (zero padding)
    }
    float acc[K_];
#pragma unroll
    for (int k = 0; k < K_; ++k) acc[k] = 0.f;
    for (int c = 0; c < C_; ++c) {
        float xv[9];
#pragma unroll
        for (int t = 0; t < 9; ++t) xv[t] = fp[(size_t)c * L_ + off[t]] * rv[t];
        const float* wc = w + c * 9;            // wave-uniform -> scalar loads
#pragma unroll
        for (int k = 0; k < K_; ++k) {
#pragma unroll
            for (int t = 0; t < 9; ++t)
                acc[k] = fmaf(wc[k * 2304 + t], xv[t], acc[k]);
        }
    }
    float m = -1e30f;
#pragma unroll
    for (int k = 0; k < K_; ++k) { acc[k] += b[k]; m = fmaxf(m, acc[k]); }
    float s = 0.f;
#pragma unroll
    for (int k = 0; k < K_; ++k) { acc[k] = __expf(acc[k] - m); s += acc[k]; }
    float rs = 1.0f / s;
    float* sp = sa + (size_t)n * KL_ + l;
#pragma unroll
    for (int k = 0; k < K_; ++k) sp[(size_t)k * L_] = acc[k] * rs;
}

// ---------- K3: ssum[n,k] = sum_l sa[n,k,l] ----------
__global__ __launch_bounds__(256) void k_ssum(const float* __restrict__ sa, float* __restrict__ ssum) {
    __shared__ float red[256];
    int bid = blockIdx.x;                       // n*K + k
    const float* sp = sa + (size_t)bid * L_;
    float s = 0.f;
    for (int m = 0; m < 16; ++m) s += sp[threadIdx.x + (m << 8)];
    red[threadIdx.x] = s; __syncthreads();
    for (int st = 128; st > 0; st >>= 1) {
        if (threadIdx.x < st) red[threadIdx.x] += red[threadIdx.x + st];
        __syncthreads();
    }
    if (threadIdx.x == 0) ssum[bid] = red[0];
}

// ---------- K4: up[n,k,c] += sum_l sa[n,k,l] * xn[n,c,l]  (atomic partial over l-slices) ----------
__global__ __launch_bounds__(256) void k_einsum(
    const float* __restrict__ f, const float* __restrict__ rinv,
    const float* __restrict__ sa, float* __restrict__ up)
{
    __shared__ float xn_s[C_ * 33];             // 33792 B
    __shared__ float sa_s[K_ * 32];             // 4096 B
    int bid = blockIdx.x;                       // 512
    int n = bid >> 5;
    int l0 = (bid & 31) << 7;                   // 128-l slice
    int tid = threadIdx.x;
    int kq = tid >> 5, cq = tid & 31;
    float acc[4][8];
#pragma unroll
    for (int i = 0; i < 4; ++i)
#pragma unroll
        for (int j = 0; j < 8; ++j) acc[i][j] = 0.f;

    for (int ch = 0; ch < 4; ++ch) {
        int lc = l0 + (ch << 5);
        __syncthreads();
        {   // stage xn = f * rinv : 256c x 32l
            int crow = tid >> 3, lq = (tid & 7) << 2;
#pragma unroll
            for (int p = 0; p < 8; ++p) {
                int c = (p << 5) + crow;
                float4 f4 = *(const float4*)(f + (size_t)n * CL_ + (size_t)c * L_ + lc + lq);
                float4 r4 = *(const float4*)(rinv + n * L_ + lc + lq);
                float* d = xn_s + c * 33 + lq;  // stride 33: unaligned for float4 -> scalar stores
                d[0] = f4.x * r4.x; d[1] = f4.y * r4.y; d[2] = f4.z * r4.z; d[3] = f4.w * r4.w;
            }
        }
        {   // stage sa : 32k x 32l
            int k = tid >> 3, lq = (tid & 7) << 2;
            float4 a4 = *(const float4*)(sa + (size_t)n * KL_ + (size_t)k * L_ + lc + lq);
            *(float4*)(sa_s + (k << 5) + lq) = a4;
        }
        __syncthreads();
#pragma unroll 4
        for (int l = 0; l < 32; ++l) {
            float sv[4], xv[8];
#pragma unroll
            for (int i = 0; i < 4; ++i) sv[i] = sa_s[((kq << 2) + i) * 32 + l];
#pragma unroll
            for (int j = 0; j < 8; ++j) xv[j] = xn_s[(cq + (j << 5)) * 33 + l];
#pragma unroll
            for (int i = 0; i < 4; ++i)
#pragma unroll
                for (int j = 0; j < 8; ++j) acc[i][j] = fmaf(sv[i], xv[j], acc[i][j]);
        }
    }
    float* upp = up + (size_t)n * KC_;
#pragma unroll
    for (int i = 0; i < 4; ++i)
#pragma unroll
        for (int j = 0; j < 8; ++j)
            atomicAdd(upp + ((kq << 2) + i) * C_ + cq + (j << 5), acc[i][j]);
}

// ---------- K5: subtract centroid term, l2norm rows, record row sumsq ----------
__global__ __launch_bounds__(256) void k_rowfix(
    const float* __restrict__ up, const float* __restrict__ ssum,
    const float* __restrict__ cent, float* __restrict__ upn, float* __restrict__ rowss)
{
    __shared__ float red[256];
    int bid = blockIdx.x;                       // n*K + k
    int k = bid & 31;
    float sv = ssum[bid];
    float v = up[(size_t)bid * C_ + threadIdx.x] - sv * cent[k * C_ + threadIdx.x];
    red[threadIdx.x] = v * v; __syncthreads();
    for (int st = 128; st > 0; st >>= 1) {
        if (threadIdx.x < st) red[threadIdx.x] += red[threadIdx.x + st];
        __syncthreads();
    }
    float ss = red[0];
    float ri = 1.0f / fmaxf(sqrtf(ss), 1e-12f);
    upn[(size_t)bid * C_ + threadIdx.x] = v * ri;
    if (threadIdx.x == 0) rowss[bid] = ss * ri * ri;
}

// ---------- K6: global l2norm + FC: upvec[n,c] = rn * (upn[n,:] . upfc_w[c,:]) + b[c] ----------
__global__ __launch_bounds__(256) void k_fc(
    const float* __restrict__ upn, const float* __restrict__ rowss,
    const float* __restrict__ w, const float* __restrict__ b,
    float* __restrict__ upvec)
{
    int bid = blockIdx.x;                       // 64
    int n = bid >> 2, cb = bid & 3;
    float ts = 0.f;
#pragma unroll
    for (int k = 0; k < K_; ++k) ts += rowss[(n << 5) + k];
    float rn = 1.0f / fmaxf(sqrtf(ts), 1e-12f);
    int wv = threadIdx.x >> 6, lane = threadIdx.x & 63;
    const float* un = upn + (size_t)n * KC_;
    for (int m = 0; m < 16; ++m) {
        int c = (cb << 6) + (wv << 4) + m;
        const float* wr = w + (size_t)c * KC_;
        float a = 0.f;
        for (int t = 0; t < 32; ++t) {
            int kc = (lane << 2) + (t << 8);
            float4 u4 = *(const float4*)(un + kc);
            float4 w4 = *(const float4*)(wr + kc);
            a += u4.x * w4.x + u4.y * w4.y + u4.z * w4.z + u4.w * w4.w;
        }
#pragma unroll
        for (int s = 32; s > 0; s >>= 1) a += __shfl_down(a, s, 64);
        if (lane == 0) upvec[n * C_ + c] = a * rn + b[c];
    }
}

// ---------- K7: t1up[n,co] = t1_w[co,256:512] . upvec[n,:] + t1_b[co] ----------
__global__ __launch_bounds__(256) void k_t1up(
    const float* __restrict__ upvec, const float* __restrict__ t1w,
    const float* __restrict__ t1b, float* __restrict__ t1up)
{
    int n = blockIdx.x;
    int wv = threadIdx.x >> 6, lane = threadIdx.x & 63;
    float4 u4 = *(const float4*)(upvec + n * C_ + (lane << 2));
    for (int q = 0; q < 64; ++q) {
        int co = (wv << 6) + q;
        float4 w4 = *(const float4*)(t1w + (size_t)co * 512 + 256 + (lane << 2));
        float a = u4.x * w4.x + u4.y * w4.y + u4.z * w4.z + u4.w * w4.w;
#pragma unroll
        for (int s = 32; s > 0; s >>= 1) a += __shfl_down(a, s, 64);
        if (lane == 0) t1up[n * C_ + co] = a + t1b[co];
    }
}

// ---------- K8/K9: 1x1 conv GEMM: Y[n,co,px] = relu( sum_ci W[co,ci]*X[n,ci,px] + bias ) ----------
__global__ __launch_bounds__(256) void k_gemm(
    const float* __restrict__ X, const float* __restrict__ Wt, int wstr,
    const float* __restrict__ bias, int bias_per_n,
    float* __restrict__ Y)
{
    __shared__ float W_s[128 * 36];             // 18432 B
    __shared__ float F_s[32 * 132];             // 16896 B
    int bid = blockIdx.x;                       // 1024
    int cb = bid >> 9, pb = bid & 511;
    int n = pb >> 5;
    int l0 = (pb & 31) << 7;
    int tid = threadIdx.x;
    int coq = tid >> 4, pxq = tid & 15;
    int co0 = cb << 7;
    float acc[8][8];
#pragma unroll
    for (int i = 0; i < 8; ++i)
#pragma unroll
        for (int j = 0; j < 8; ++j) acc[i][j] = 0.f;

    for (int s = 0; s < 8; ++s) {
        int ci0 = s << 5;
        __syncthreads();
        {   // stage W: 128co x 32ci
            int co_l = tid >> 1, ci_l = (tid & 1) << 4;
            const float* src = Wt + (size_t)(co0 + co_l) * wstr + ci0 + ci_l;
            float* dst = W_s + co_l * 36 + ci_l;
#pragma unroll
            for (int u = 0; u < 4; ++u)
                *(float4*)(dst + (u << 2)) = *(const float4*)(src + (u << 2));
        }
        {   // stage F: 32ci x 128px
            int ci = tid >> 3, pq = (tid & 7) << 4;
            const float* src = X + (size_t)n * CL_ + (size_t)(ci0 + ci) * L_ + l0 + pq;
            float* dst = F_s + ci * 132 + pq;
#pragma unroll
            for (int u = 0; u < 4; ++u)
                *(float4*)(dst + (u << 2)) = *(const float4*)(src + (u << 2));
        }
        __syncthreads();
#pragma unroll 8
        for (int ci = 0; ci < 32; ++ci) {
            float wv[8], xv[8];
#pragma unroll
            for (int i = 0; i < 8; ++i) wv[i] = W_s[(coq + (i << 4)) * 36 + ci];
#pragma unroll
            for (int j = 0; j < 8; ++j) xv[j] = F_s[ci * 132 + pxq + (j << 4)];
#pragma unroll
            for (int i = 0; i < 8; ++i)
#pragma unroll
                for (int j = 0; j < 8; ++j) acc[i][j] = fmaf(wv[i], xv[j], acc[i][j]);
        }
    }
    const float* bp = bias + (bias_per_n ? n * C_ : 0);
#pragma unroll
    for (int i = 0; i < 8; ++i) {
        int co = co0 + coq + (i << 4);
        float bv = bp[co];
        float* yp = Y + (size_t)n * CL_ + (size_t)co * L_ + l0 + pxq;
#pragma unroll
        for (int j = 0; j < 8; ++j)
            yp[j << 4] = fmaxf(acc[i][j] + bv, 0.f);
    }
}

extern "C" void kernel_launch(void* const* d_in, const int* in_sizes, int n_in,
                              void* d_out, int out_size, void* d_ws, size_t ws_size,
                              hipStream_t stream)
{
    const float* feature = (const float*)d_in[0];
    const float* conv_w  = (const float*)d_in[1];
    const float* conv_b  = (const float*)d_in[2];
    const float* cent    = (const float*)d_in[3];
    const float* upfc_w  = (const float*)d_in[4];
    const float* upfc_b  = (const float*)d_in[5];
    const float* t1w     = (const float*)d_in[6];
    const float* t1b     = (const float*)d_in[7];
    const float* t2w     = (const float*)d_in[8];
    const float* t2b     = (const float*)d_in[9];

    float* ws    = (float*)d_ws;                 // ~76.8 MB used
    float* rinv  = ws;                           // 65536
    float* sa    = rinv + 65536;                 // 2097152
    float* up    = sa + 2097152;                 // 131072
    float* upn   = up + 131072;                  // 131072
    float* ssum  = upn + 131072;                 // 512
    float* rowss = ssum + 512;                   // 512
    float* upvec = rowss + 512;                  // 4096
    float* t1up  = upvec + 4096;                 // 4096
    float* h     = t1up + 4096;                  // 16777216
    float* out   = (float*)d_out;

    hipMemsetAsync(up, 0, 131072 * sizeof(float), stream);
    k_rinv        <<<256, 256, 0, stream>>>(feature, rinv);
    k_conv_softmax<<<512, 128, 0, stream>>>(feature, rinv, conv_w, conv_b, sa);
    k_ssum        <<<512, 256, 0, stream>>>(sa, ssum);
    k_einsum      <<<512, 256, 0, stream>>>(feature, rinv, sa, up);
    k_rowfix      <<<512, 256, 0, stream>>>(up, ssum, cent, upn, rowss);
    k_fc          <<<64,  256, 0, stream>>>(upn, rowss, upfc_w, upfc_b, upvec);
    k_t1up        <<<16,  256, 0, stream>>>(upvec, t1w, t1b, t1up);
    k_gemm        <<<1024, 256, 0, stream>>>(feature, t1w, 512, t1up, 1, h);
    k_gemm        <<<1024, 256, 0, stream>>>(h,       t2w, 256, t2b, 0, out);
}

// Round 2
// 1014.110 us; speedup vs baseline: 1.7263x; 1.7263x over previous
//
#include <hip/hip_runtime.h>
#include <cstdint>

#define N_ 16
#define C_ 256
#define H_ 64
#define W_ 64
#define L_ 4096          // H*W
#define K_ 32
#define CL_ (C_*L_)      // 1048576
#define KL_ (K_*L_)      // 131072
#define KC_ (K_*C_)      // 8192

// ---------- K1: per-pixel 1/max(||x||,eps) ----------
__global__ __launch_bounds__(256) void k_rinv(const float* __restrict__ f, float* __restrict__ rinv) {
    int p = blockIdx.x * 256 + threadIdx.x;          // 0..65535
    int n = p >> 12, l = p & (L_ - 1);
    const float* fp = f + (size_t)n * CL_ + l;
    float s = 0.f;
#pragma unroll 8
    for (int c = 0; c < C_; ++c) { float v = fp[(size_t)c * L_]; s = fmaf(v, v, s); }
    rinv[p] = 1.0f / fmaxf(sqrtf(s), 1e-12f);
}

// ---------- K2a: partial 3x3 conv over a 32-channel chunk ----------
// grid: 8 chunks x 16 n x 16 row-groups = 2048 blocks x 256 threads (8192 waves)
// logits[chunk][n][k][l] — aliased onto the 64 MB `h` buffer (consumed before h is written)
__global__ __launch_bounds__(256) void k_conv_part(
    const float* __restrict__ f, const float* __restrict__ rinv,
    const float* __restrict__ w, float* __restrict__ logits)
{
    int bid = blockIdx.x;
    int chunk = bid >> 8;                       // 0..7
    int n = (bid >> 4) & 15;
    int rg = bid & 15;                          // group of 4 rows
    int y = (rg << 2) + (threadIdx.x >> 6);
    int x = threadIdx.x & 63;
    int l = (y << 6) + x;
    const float* fp = f + (size_t)n * CL_ + (size_t)(chunk << 5) * L_;
    const float* rp = rinv + n * L_;
    int off[9]; float rv[9];
#pragma unroll
    for (int t = 0; t < 9; ++t) {
        int dy = t / 3 - 1, dx = t % 3 - 1;
        int yy = y + dy, xx = x + dx;
        bool ok = (yy >= 0 && yy < H_ && xx >= 0 && xx < W_);
        int o = (ok ? yy : y) * W_ + (ok ? xx : x);
        off[t] = o;
        rv[t] = ok ? rp[o] : 0.f;               // invalid taps contribute 0 (zero padding)
    }
    float acc[K_];
#pragma unroll
    for (int k = 0; k < K_; ++k) acc[k] = 0.f;
    const float* wc0 = w + (chunk << 5) * 9;    // w[k][c][t], c-chunk base
    for (int c = 0; c < 32; ++c) {
        float xv[9];
#pragma unroll
        for (int t = 0; t < 9; ++t) xv[t] = fp[(size_t)c * L_ + off[t]] * rv[t];
        const float* wc = wc0 + c * 9;          // wave-uniform -> scalar loads
#pragma unroll
        for (int k = 0; k < K_; ++k) {
#pragma unroll
            for (int t = 0; t < 9; ++t)
                acc[k] = fmaf(wc[k * 2304 + t], xv[t], acc[k]);
        }
    }
    float* op = logits + (size_t)chunk * (N_ * (size_t)KL_) + (size_t)n * KL_ + l;
#pragma unroll
    for (int k = 0; k < K_; ++k) op[(size_t)k * L_] = acc[k];
}

// ---------- K2b: sum 8 partials + bias + softmax over K ----------
__global__ __launch_bounds__(256) void k_softmax(
    const float* __restrict__ logits, const float* __restrict__ b,
    float* __restrict__ sa)
{
    int p = blockIdx.x * 256 + threadIdx.x;     // 0..65535
    int n = p >> 12, l = p & (L_ - 1);
    float acc[K_];
#pragma unroll
    for (int k = 0; k < K_; ++k) acc[k] = b[k];
    const float* base = logits + (size_t)n * KL_ + l;
    for (int ch = 0; ch < 8; ++ch) {
        const float* cp = base + (size_t)ch * (N_ * (size_t)KL_);
#pragma unroll
        for (int k = 0; k < K_; ++k) acc[k] += cp[(size_t)k * L_];
    }
    float m = -1e30f;
#pragma unroll
    for (int k = 0; k < K_; ++k) m = fmaxf(m, acc[k]);
    float s = 0.f;
#pragma unroll
    for (int k = 0; k < K_; ++k) { acc[k] = __expf(acc[k] - m); s += acc[k]; }
    float rs = 1.0f / s;
    float* sp = sa + (size_t)n * KL_ + l;
#pragma unroll
    for (int k = 0; k < K_; ++k) sp[(size_t)k * L_] = acc[k] * rs;
}

// ---------- K3: ssum[n,k] = sum_l sa[n,k,l] ----------
__global__ __launch_bounds__(256) void k_ssum(const float* __restrict__ sa, float* __restrict__ ssum) {
    __shared__ float red[256];
    int bid = blockIdx.x;                       // n*K + k
    const float* sp = sa + (size_t)bid * L_;
    float s = 0.f;
    for (int m = 0; m < 16; ++m) s += sp[threadIdx.x + (m << 8)];
    red[threadIdx.x] = s; __syncthreads();
    for (int st = 128; st > 0; st >>= 1) {
        if (threadIdx.x < st) red[threadIdx.x] += red[threadIdx.x + st];
        __syncthreads();
    }
    if (threadIdx.x == 0) ssum[bid] = red[0];
}

// ---------- K4: up[n,k,c] += sum_l sa[n,k,l] * xn[n,c,l]  (atomic partial over l-slices) ----------
__global__ __launch_bounds__(256) void k_einsum(
    const float* __restrict__ f, const float* __restrict__ rinv,
    const float* __restrict__ sa, float* __restrict__ up)
{
    __shared__ float xn_s[C_ * 33];             // 33792 B
    __shared__ float sa_s[K_ * 32];             // 4096 B
    int bid = blockIdx.x;                       // 512
    int n = bid >> 5;
    int l0 = (bid & 31) << 7;                   // 128-l slice
    int tid = threadIdx.x;
    int kq = tid >> 5, cq = tid & 31;
    float acc[4][8];
#pragma unroll
    for (int i = 0; i < 4; ++i)
#pragma unroll
        for (int j = 0; j < 8; ++j) acc[i][j] = 0.f;

    for (int ch = 0; ch < 4; ++ch) {
        int lc = l0 + (ch << 5);
        __syncthreads();
        {   // stage xn = f * rinv : 256c x 32l
            int crow = tid >> 3, lq = (tid & 7) << 2;
#pragma unroll
            for (int p = 0; p < 8; ++p) {
                int c = (p << 5) + crow;
                float4 f4 = *(const float4*)(f + (size_t)n * CL_ + (size_t)c * L_ + lc + lq);
                float4 r4 = *(const float4*)(rinv + n * L_ + lc + lq);
                float* d = xn_s + c * 33 + lq;
                d[0] = f4.x * r4.x; d[1] = f4.y * r4.y; d[2] = f4.z * r4.z; d[3] = f4.w * r4.w;
            }
        }
        {   // stage sa : 32k x 32l
            int k = tid >> 3, lq = (tid & 7) << 2;
            float4 a4 = *(const float4*)(sa + (size_t)n * KL_ + (size_t)k * L_ + lc + lq);
            *(float4*)(sa_s + (k << 5) + lq) = a4;
        }
        __syncthreads();
#pragma unroll 4
        for (int l = 0; l < 32; ++l) {
            float sv[4], xv[8];
#pragma unroll
            for (int i = 0; i < 4; ++i) sv[i] = sa_s[((kq << 2) + i) * 32 + l];
#pragma unroll
            for (int j = 0; j < 8; ++j) xv[j] = xn_s[(cq + (j << 5)) * 33 + l];
#pragma unroll
            for (int i = 0; i < 4; ++i)
#pragma unroll
                for (int j = 0; j < 8; ++j) acc[i][j] = fmaf(sv[i], xv[j], acc[i][j]);
        }
    }
    float* upp = up + (size_t)n * KC_;
#pragma unroll
    for (int i = 0; i < 4; ++i)
#pragma unroll
        for (int j = 0; j < 8; ++j)
            atomicAdd(upp + ((kq << 2) + i) * C_ + cq + (j << 5), acc[i][j]);
}

// ---------- K5: subtract centroid term, l2norm rows, record row sumsq ----------
__global__ __launch_bounds__(256) void k_rowfix(
    const float* __restrict__ up, const float* __restrict__ ssum,
    const float* __restrict__ cent, float* __restrict__ upn, float* __restrict__ rowss)
{
    __shared__ float red[256];
    int bid = blockIdx.x;                       // n*K + k
    int k = bid & 31;
    float sv = ssum[bid];
    float v = up[(size_t)bid * C_ + threadIdx.x] - sv * cent[k * C_ + threadIdx.x];
    red[threadIdx.x] = v * v; __syncthreads();
    for (int st = 128; st > 0; st >>= 1) {
        if (threadIdx.x < st) red[threadIdx.x] += red[threadIdx.x + st];
        __syncthreads();
    }
    float ss = red[0];
    float ri = 1.0f / fmaxf(sqrtf(ss), 1e-12f);
    upn[(size_t)bid * C_ + threadIdx.x] = v * ri;
    if (threadIdx.x == 0) rowss[bid] = ss * ri * ri;
}

// ---------- K6: global l2norm + FC: upvec[n,c] = rn * (upn[n,:] . upfc_w[c,:]) + b[c] ----------
__global__ __launch_bounds__(256) void k_fc(
    const float* __restrict__ upn, const float* __restrict__ rowss,
    const float* __restrict__ w, const float* __restrict__ b,
    float* __restrict__ upvec)
{
    int bid = blockIdx.x;                       // 64
    int n = bid >> 2, cb = bid & 3;
    float ts = 0.f;
#pragma unroll
    for (int k = 0; k < K_; ++k) ts += rowss[(n << 5) + k];
    float rn = 1.0f / fmaxf(sqrtf(ts), 1e-12f);
    int wv = threadIdx.x >> 6, lane = threadIdx.x & 63;
    const float* un = upn + (size_t)n * KC_;
    for (int m = 0; m < 16; ++m) {
        int c = (cb << 6) + (wv << 4) + m;
        const float* wr = w + (size_t)c * KC_;
        float a = 0.f;
        for (int t = 0; t < 32; ++t) {
            int kc = (lane << 2) + (t << 8);
            float4 u4 = *(const float4*)(un + kc);
            float4 w4 = *(const float4*)(wr + kc);
            a += u4.x * w4.x + u4.y * w4.y + u4.z * w4.z + u4.w * w4.w;
        }
#pragma unroll
        for (int s = 32; s > 0; s >>= 1) a += __shfl_down(a, s, 64);
        if (lane == 0) upvec[n * C_ + c] = a * rn + b[c];
    }
}

// ---------- K7: t1up[n,co] = t1_w[co,256:512] . upvec[n,:] + t1_b[co] ----------
__global__ __launch_bounds__(256) void k_t1up(
    const float* __restrict__ upvec, const float* __restrict__ t1w,
    const float* __restrict__ t1b, float* __restrict__ t1up)
{
    int n = blockIdx.x;
    int wv = threadIdx.x >> 6, lane = threadIdx.x & 63;
    float4 u4 = *(const float4*)(upvec + n * C_ + (lane << 2));
    for (int q = 0; q < 64; ++q) {
        int co = (wv << 6) + q;
        float4 w4 = *(const float4*)(t1w + (size_t)co * 512 + 256 + (lane << 2));
        float a = u4.x * w4.x + u4.y * w4.y + u4.z * w4.z + u4.w * w4.w;
#pragma unroll
        for (int s = 32; s > 0; s >>= 1) a += __shfl_down(a, s, 64);
        if (lane == 0) t1up[n * C_ + co] = a + t1b[co];
    }
}

// ---------- K8/K9: 1x1 conv GEMM: Y[n,co,px] = relu( sum_ci W[co,ci]*X[n,ci,px] + bias ) ----------
__global__ __launch_bounds__(256) void k_gemm(
    const float* __restrict__ X, const float* __restrict__ Wt, int wstr,
    const float* __restrict__ bias, int bias_per_n,
    float* __restrict__ Y)
{
    __shared__ float W_s[128 * 36];             // 18432 B
    __shared__ float F_s[32 * 132];             // 16896 B
    int bid = blockIdx.x;                       // 1024
    int cb = bid >> 9, pb = bid & 511;
    int n = pb >> 5;
    int l0 = (pb & 31) << 7;
    int tid = threadIdx.x;
    int coq = tid >> 4, pxq = tid & 15;
    int co0 = cb << 7;
    float acc[8][8];
#pragma unroll
    for (int i = 0; i < 8; ++i)
#pragma unroll
        for (int j = 0; j < 8; ++j) acc[i][j] = 0.f;

    for (int s = 0; s < 8; ++s) {
        int ci0 = s << 5;
        __syncthreads();
        {   // stage W: 128co x 32ci
            int co_l = tid >> 1, ci_l = (tid & 1) << 4;
            const float* src = Wt + (size_t)(co0 + co_l) * wstr + ci0 + ci_l;
            float* dst = W_s + co_l * 36 + ci_l;
#pragma unroll
            for (int u = 0; u < 4; ++u)
                *(float4*)(dst + (u << 2)) = *(const float4*)(src + (u << 2));
        }
        {   // stage F: 32ci x 128px
            int ci = tid >> 3, pq = (tid & 7) << 4;
            const float* src = X + (size_t)n * CL_ + (size_t)(ci0 + ci) * L_ + l0 + pq;
            float* dst = F_s + ci * 132 + pq;
#pragma unroll
            for (int u = 0; u < 4; ++u)
                *(float4*)(dst + (u << 2)) = *(const float4*)(src + (u << 2));
        }
        __syncthreads();
#pragma unroll 8
        for (int ci = 0; ci < 32; ++ci) {
            float wv[8], xv[8];
#pragma unroll
            for (int i = 0; i < 8; ++i) wv[i] = W_s[(coq + (i << 4)) * 36 + ci];
#pragma unroll
            for (int j = 0; j < 8; ++j) xv[j] = F_s[ci * 132 + pxq + (j << 4)];
#pragma unroll
            for (int i = 0; i < 8; ++i)
#pragma unroll
                for (int j = 0; j < 8; ++j) acc[i][j] = fmaf(wv[i], xv[j], acc[i][j]);
        }
    }
    const float* bp = bias + (bias_per_n ? n * C_ : 0);
#pragma unroll
    for (int i = 0; i < 8; ++i) {
        int co = co0 + coq + (i << 4);
        float bv = bp[co];
        float* yp = Y + (size_t)n * CL_ + (size_t)co * L_ + l0 + pxq;
#pragma unroll
        for (int j = 0; j < 8; ++j)
            yp[j << 4] = fmaxf(acc[i][j] + bv, 0.f);
    }
}

extern "C" void kernel_launch(void* const* d_in, const int* in_sizes, int n_in,
                              void* d_out, int out_size, void* d_ws, size_t ws_size,
                              hipStream_t stream)
{
    const float* feature = (const float*)d_in[0];
    const float* conv_w  = (const float*)d_in[1];
    const float* conv_b  = (const float*)d_in[2];
    const float* cent    = (const float*)d_in[3];
    const float* upfc_w  = (const float*)d_in[4];
    const float* upfc_b  = (const float*)d_in[5];
    const float* t1w     = (const float*)d_in[6];
    const float* t1b     = (const float*)d_in[7];
    const float* t2w     = (const float*)d_in[8];
    const float* t2b     = (const float*)d_in[9];

    float* ws    = (float*)d_ws;                 // ~76.8 MB used
    float* rinv  = ws;                           // 65536
    float* sa    = rinv + 65536;                 // 2097152
    float* up    = sa + 2097152;                 // 131072
    float* upn   = up + 131072;                  // 131072
    float* ssum  = upn + 131072;                 // 512
    float* rowss = ssum + 512;                   // 512
    float* upvec = rowss + 512;                  // 4096
    float* t1up  = upvec + 4096;                 // 4096
    float* h     = t1up + 4096;                  // 16777216 floats (64 MB)
    float* logits = h;                           // alias: consumed by k_softmax before k_gemm writes h
    float* out   = (float*)d_out;

    hipMemsetAsync(up, 0, 131072 * sizeof(float), stream);
    k_rinv     <<<256,  256, 0, stream>>>(feature, rinv);
    k_conv_part<<<2048, 256, 0, stream>>>(feature, rinv, conv_w, logits);
    k_softmax  <<<256,  256, 0, stream>>>(logits, conv_b, sa);
    k_ssum     <<<512,  256, 0, stream>>>(sa, ssum);
    k_einsum   <<<512,  256, 0, stream>>>(feature, rinv, sa, up);
    k_rowfix   <<<512,  256, 0, stream>>>(up, ssum, cent, upn, rowss);
    k_fc       <<<64,   256, 0, stream>>>(upn, rowss, upfc_w, upfc_b, upvec);
    k_t1up     <<<16,   256, 0, stream>>>(upvec, t1w, t1b, t1up);
    k_gemm     <<<1024, 256, 0, stream>>>(feature, t1w, 512, t1up, 1, h);
    k_gemm     <<<1024, 256, 0, stream>>>(h,       t2w, 256, t2b, 0, out);
}

// Round 3
// 717.430 us; speedup vs baseline: 2.4402x; 1.4135x over previous
//
#include <hip/hip_runtime.h>
#include <cstdint>

#define N_ 16
#define C_ 256
#define H_ 64
#define W_ 64
#define L_ 4096          // H*W
#define K_ 32
#define CL_ (C_*L_)      // 1048576
#define KL_ (K_*L_)      // 131072
#define KC_ (K_*C_)      // 8192

typedef __attribute__((ext_vector_type(8))) short short8;   // 8 bf16 (4 VGPRs)
typedef __attribute__((ext_vector_type(4))) float f32x4;    // MFMA C/D frag

__device__ __forceinline__ unsigned short f2bf(float x) {   // RNE fp32->bf16
    unsigned int u = __float_as_uint(x);
    u += 0x7fffu + ((u >> 16) & 1u);
    return (unsigned short)(u >> 16);
}

// ---------- K1: fused rinv + xn(bf16) transpose to (n,l,c) ----------
// grid: 16 n x 128 strips (32 l each) = 2048 blocks x 256 threads
__global__ __launch_bounds__(256) void k_prep(
    const float* __restrict__ f, float* __restrict__ rinv, unsigned short* __restrict__ xnb)
{
    __shared__ float tile[256 * 34];            // [c][l], stride 34 (conflict-free)
    __shared__ float ssred[8 * 33];
    __shared__ float rbuf[32];
    int bid = blockIdx.x;
    int n = bid >> 7;
    int l0 = (bid & 127) << 5;
    int tid = threadIdx.x;
    int l = tid & 31, cb = tid >> 5;            // cb 0..7
    const float* fp = f + (size_t)n * CL_ + l0 + l;
    float ss = 0.f;
#pragma unroll
    for (int i = 0; i < 32; ++i) {
        int c = (cb << 5) + i;
        float v = fp[(size_t)c * L_];
        tile[c * 34 + l] = v;
        ss = fmaf(v, v, ss);
    }
    ssred[cb * 33 + l] = ss;
    __syncthreads();
    if (tid < 32) {
        float s = 0.f;
#pragma unroll
        for (int j = 0; j < 8; ++j) s += ssred[j * 33 + tid];
        float ri = 1.0f / fmaxf(sqrtf(s), 1e-12f);
        rinv[n * L_ + l0 + tid] = ri;
        rbuf[tid] = ri;
    }
    __syncthreads();
    float ri = rbuf[l];
    unsigned short* op = xnb + ((size_t)n * L_ + l0 + l) * C_ + (cb << 5);
#pragma unroll
    for (int g = 0; g < 4; ++g) {
        unsigned int pk[4];
#pragma unroll
        for (int d = 0; d < 4; ++d) {
            int c = (cb << 5) + (g << 3) + (d << 1);
            unsigned int lo = f2bf(tile[c * 34 + l] * ri);
            unsigned int hi = f2bf(tile[(c + 1) * 34 + l] * ri);
            pk[d] = lo | (hi << 16);
        }
        *(uint4*)(op + (g << 3)) = make_uint4(pk[0], pk[1], pk[2], pk[3]);
    }
}

// ---------- K2: repack conv weights -> wb[t][k][c] bf16 ----------
__global__ __launch_bounds__(256) void k_wpack(const float* __restrict__ w, unsigned short* __restrict__ wb) {
    int i = blockIdx.x * 256 + threadIdx.x;     // 73728
    int t = i >> 13;
    int k = (i >> 8) & 31;
    int c = i & 255;
    wb[i] = f2bf(w[k * 2304 + c * 9 + t]);
}

// ---------- K3: MFMA implicit-GEMM 3x3 conv + fused softmax over K ----------
// grid: 16 n x 32 y-pairs = 512 blocks x 256 threads (4 waves; wave = one row-half = 32 px)
__global__ __launch_bounds__(256) void k_conv_mfma(
    const unsigned short* __restrict__ xnb, const unsigned short* __restrict__ wb,
    const float* __restrict__ bias, float* __restrict__ sa)
{
    int bid = blockIdx.x;
    int n = bid >> 5;
    int y0 = (bid & 31) << 1;
    int wv = threadIdx.x >> 6, lane = threadIdx.x & 63;
    int y = y0 + (wv >> 1);
    int x0 = (wv & 1) << 5;                     // 0 or 32
    int px = lane & 15, quad = lane >> 4;
    const unsigned short* xb = xnb + (size_t)n * CL_;   // (l, c) bf16
    short8 zz = {0, 0, 0, 0, 0, 0, 0, 0};
    f32x4 acc[2][2];
#pragma unroll
    for (int pt = 0; pt < 2; ++pt)
#pragma unroll
        for (int m = 0; m < 2; ++m) acc[pt][m] = (f32x4){0.f, 0.f, 0.f, 0.f};

    for (int c0 = 0; c0 < 256; c0 += 32) {
        short8 a[9][2];
#pragma unroll
        for (int t = 0; t < 9; ++t)
#pragma unroll
            for (int m = 0; m < 2; ++m)
                a[t][m] = *(const short8*)(wb + t * 8192 + ((m << 4) + px) * 256 + c0 + (quad << 3));
#pragma unroll
        for (int t = 0; t < 9; ++t) {
            int dy = t / 3 - 1, dx = t % 3 - 1;
            int yy = y + dy;
            if ((unsigned)yy < 64u) {           // wave-uniform row validity
#pragma unroll
                for (int pt = 0; pt < 2; ++pt) {
                    int xx = x0 + (pt << 4) + px + dx;
                    bool okx = (unsigned)xx < 64u;
                    int xs = okx ? xx : 0;
                    short8 b = *(const short8*)(xb + ((size_t)(yy << 6) + xs) * 256 + c0 + (quad << 3));
                    if (!okx) b = zz;           // zero-padding at x edges
                    acc[pt][0] = __builtin_amdgcn_mfma_f32_16x16x32_bf16(a[t][0], b, acc[pt][0], 0, 0, 0);
                    acc[pt][1] = __builtin_amdgcn_mfma_f32_16x16x32_bf16(a[t][1], b, acc[pt][1], 0, 0, 0);
                }
            }
        }
    }
    // fused bias + softmax over k (32 values per px, spread over 4 quads x 8 regs)
    float4 b0 = *(const float4*)(bias + (quad << 2));
    float4 b1 = *(const float4*)(bias + 16 + (quad << 2));
#pragma unroll
    for (int pt = 0; pt < 2; ++pt) {
        float v[8];
        v[0] = acc[pt][0][0] + b0.x; v[1] = acc[pt][0][1] + b0.y;
        v[2] = acc[pt][0][2] + b0.z; v[3] = acc[pt][0][3] + b0.w;
        v[4] = acc[pt][1][0] + b1.x; v[5] = acc[pt][1][1] + b1.y;
        v[6] = acc[pt][1][2] + b1.z; v[7] = acc[pt][1][3] + b1.w;
        float mx = v[0];
#pragma unroll
        for (int r = 1; r < 8; ++r) mx = fmaxf(mx, v[r]);
        mx = fmaxf(mx, __shfl_xor(mx, 16));
        mx = fmaxf(mx, __shfl_xor(mx, 32));
        float s = 0.f;
#pragma unroll
        for (int r = 0; r < 8; ++r) { v[r] = __expf(v[r] - mx); s += v[r]; }
        s += __shfl_xor(s, 16);
        s += __shfl_xor(s, 32);
        float rs = 1.0f / s;
        int l = (y << 6) + x0 + (pt << 4) + px;
        float* sp = sa + (size_t)n * KL_ + l;
#pragma unroll
        for (int r = 0; r < 4; ++r) {
            sp[(size_t)((quad << 2) + r) * L_] = v[r] * rs;
            sp[(size_t)(16 + (quad << 2) + r) * L_] = v[4 + r] * rs;
        }
    }
}

// ---------- K4: ssum[n,k] = sum_l sa[n,k,l] ----------
__global__ __launch_bounds__(256) void k_ssum(const float* __restrict__ sa, float* __restrict__ ssum) {
    __shared__ float red[256];
    int bid = blockIdx.x;                       // n*K + k
    const float* sp = sa + (size_t)bid * L_;
    float s = 0.f;
    for (int m = 0; m < 16; ++m) s += sp[threadIdx.x + (m << 8)];
    red[threadIdx.x] = s; __syncthreads();
    for (int st = 128; st > 0; st >>= 1) {
        if (threadIdx.x < st) red[threadIdx.x] += red[threadIdx.x + st];
        __syncthreads();
    }
    if (threadIdx.x == 0) ssum[bid] = red[0];
}

// ---------- K5: up[n,k,c] += sum_l sa[n,k,l] * xn[n,c,l] ----------
__global__ __launch_bounds__(256) void k_einsum(
    const float* __restrict__ f, const float* __restrict__ rinv,
    const float* __restrict__ sa, float* __restrict__ up)
{
    __shared__ float xn_s[C_ * 33];
    __shared__ float sa_s[K_ * 32];
    int bid = blockIdx.x;                       // 512
    int n = bid >> 5;
    int l0 = (bid & 31) << 7;
    int tid = threadIdx.x;
    int kq = tid >> 5, cq = tid & 31;
    float acc[4][8];
#pragma unroll
    for (int i = 0; i < 4; ++i)
#pragma unroll
        for (int j = 0; j < 8; ++j) acc[i][j] = 0.f;

    for (int ch = 0; ch < 4; ++ch) {
        int lc = l0 + (ch << 5);
        __syncthreads();
        {
            int crow = tid >> 3, lq = (tid & 7) << 2;
#pragma unroll
            for (int p = 0; p < 8; ++p) {
                int c = (p << 5) + crow;
                float4 f4 = *(const float4*)(f + (size_t)n * CL_ + (size_t)c * L_ + lc + lq);
                float4 r4 = *(const float4*)(rinv + n * L_ + lc + lq);
                float* d = xn_s + c * 33 + lq;
                d[0] = f4.x * r4.x; d[1] = f4.y * r4.y; d[2] = f4.z * r4.z; d[3] = f4.w * r4.w;
            }
        }
        {
            int k = tid >> 3, lq = (tid & 7) << 2;
            float4 a4 = *(const float4*)(sa + (size_t)n * KL_ + (size_t)k * L_ + lc + lq);
            *(float4*)(sa_s + (k << 5) + lq) = a4;
        }
        __syncthreads();
#pragma unroll 4
        for (int l = 0; l < 32; ++l) {
            float sv[4], xv[8];
#pragma unroll
            for (int i = 0; i < 4; ++i) sv[i] = sa_s[((kq << 2) + i) * 32 + l];
#pragma unroll
            for (int j = 0; j < 8; ++j) xv[j] = xn_s[(cq + (j << 5)) * 33 + l];
#pragma unroll
            for (int i = 0; i < 4; ++i)
#pragma unroll
                for (int j = 0; j < 8; ++j) acc[i][j] = fmaf(sv[i], xv[j], acc[i][j]);
        }
    }
    float* upp = up + (size_t)n * KC_;
#pragma unroll
    for (int i = 0; i < 4; ++i)
#pragma unroll
        for (int j = 0; j < 8; ++j)
            atomicAdd(upp + ((kq << 2) + i) * C_ + cq + (j << 5), acc[i][j]);
}

// ---------- K6: subtract centroid term, l2norm rows, record row sumsq ----------
__global__ __launch_bounds__(256) void k_rowfix(
    const float* __restrict__ up, const float* __restrict__ ssum,
    const float* __restrict__ cent, float* __restrict__ upn, float* __restrict__ rowss)
{
    __shared__ float red[256];
    int bid = blockIdx.x;                       // n*K + k
    int k = bid & 31;
    float sv = ssum[bid];
    float v = up[(size_t)bid * C_ + threadIdx.x] - sv * cent[k * C_ + threadIdx.x];
    red[threadIdx.x] = v * v; __syncthreads();
    for (int st = 128; st > 0; st >>= 1) {
        if (threadIdx.x < st) red[threadIdx.x] += red[threadIdx.x + st];
        __syncthreads();
    }
    float ss = red[0];
    float ri = 1.0f / fmaxf(sqrtf(ss), 1e-12f);
    upn[(size_t)bid * C_ + threadIdx.x] = v * ri;
    if (threadIdx.x == 0) rowss[bid] = ss * ri * ri;
}

// ---------- K7: global l2norm + FC ----------
__global__ __launch_bounds__(256) void k_fc(
    const float* __restrict__ upn, const float* __restrict__ rowss,
    const float* __restrict__ w, const float* __restrict__ b,
    float* __restrict__ upvec)
{
    int bid = blockIdx.x;                       // 64
    int n = bid >> 2, cb = bid & 3;
    float ts = 0.f;
#pragma unroll
    for (int k = 0; k < K_; ++k) ts += rowss[(n << 5) + k];
    float rn = 1.0f / fmaxf(sqrtf(ts), 1e-12f);
    int wv = threadIdx.x >> 6, lane = threadIdx.x & 63;
    const float* un = upn + (size_t)n * KC_;
    for (int m = 0; m < 16; ++m) {
        int c = (cb << 6) + (wv << 4) + m;
        const float* wr = w + (size_t)c * KC_;
        float a = 0.f;
        for (int t = 0; t < 32; ++t) {
            int kc = (lane << 2) + (t << 8);
            float4 u4 = *(const float4*)(un + kc);
            float4 w4 = *(const float4*)(wr + kc);
            a += u4.x * w4.x + u4.y * w4.y + u4.z * w4.z + u4.w * w4.w;
        }
#pragma unroll
        for (int s = 32; s > 0; s >>= 1) a += __shfl_down(a, s, 64);
        if (lane == 0) upvec[n * C_ + c] = a * rn + b[c];
    }
}

// ---------- K8: t1up[n,co] = t1_w[co,256:512] . upvec[n,:] + t1_b[co] ----------
__global__ __launch_bounds__(256) void k_t1up(
    const float* __restrict__ upvec, const float* __restrict__ t1w,
    const float* __restrict__ t1b, float* __restrict__ t1up)
{
    int n = blockIdx.x;
    int wv = threadIdx.x >> 6, lane = threadIdx.x & 63;
    float4 u4 = *(const float4*)(upvec + n * C_ + (lane << 2));
    for (int q = 0; q < 64; ++q) {
        int co = (wv << 6) + q;
        float4 w4 = *(const float4*)(t1w + (size_t)co * 512 + 256 + (lane << 2));
        float a = u4.x * w4.x + u4.y * w4.y + u4.z * w4.z + u4.w * w4.w;
#pragma unroll
        for (int s = 32; s > 0; s >>= 1) a += __shfl_down(a, s, 64);
        if (lane == 0) t1up[n * C_ + co] = a + t1b[co];
    }
}

// ---------- K9/K10: 1x1 conv GEMM ----------
__global__ __launch_bounds__(256) void k_gemm(
    const float* __restrict__ X, const float* __restrict__ Wt, int wstr,
    const float* __restrict__ bias, int bias_per_n,
    float* __restrict__ Y)
{
    __shared__ float W_s[128 * 36];
    __shared__ float F_s[32 * 132];
    int bid = blockIdx.x;                       // 1024
    int cb = bid >> 9, pb = bid & 511;
    int n = pb >> 5;
    int l0 = (pb & 31) << 7;
    int tid = threadIdx.x;
    int coq = tid >> 4, pxq = tid & 15;
    int co0 = cb << 7;
    float acc[8][8];
#pragma unroll
    for (int i = 0; i < 8; ++i)
#pragma unroll
        for (int j = 0; j < 8; ++j) acc[i][j] = 0.f;

    for (int s = 0; s < 8; ++s) {
        int ci0 = s << 5;
        __syncthreads();
        {
            int co_l = tid >> 1, ci_l = (tid & 1) << 4;
            const float* src = Wt + (size_t)(co0 + co_l) * wstr + ci0 + ci_l;
            float* dst = W_s + co_l * 36 + ci_l;
#pragma unroll
            for (int u = 0; u < 4; ++u)
                *(float4*)(dst + (u << 2)) = *(const float4*)(src + (u << 2));
        }
        {
            int ci = tid >> 3, pq = (tid & 7) << 4;
            const float* src = X + (size_t)n * CL_ + (size_t)(ci0 + ci) * L_ + l0 + pq;
            float* dst = F_s + ci * 132 + pq;
#pragma unroll
            for (int u = 0; u < 4; ++u)
                *(float4*)(dst + (u << 2)) = *(const float4*)(src + (u << 2));
        }
        __syncthreads();
#pragma unroll 8
        for (int ci = 0; ci < 32; ++ci) {
            float wv[8], xv[8];
#pragma unroll
            for (int i = 0; i < 8; ++i) wv[i] = W_s[(coq + (i << 4)) * 36 + ci];
#pragma unroll
            for (int j = 0; j < 8; ++j) xv[j] = F_s[ci * 132 + pxq + (j << 4)];
#pragma unroll
            for (int i = 0; i < 8; ++i)
#pragma unroll
                for (int j = 0; j < 8; ++j) acc[i][j] = fmaf(wv[i], xv[j], acc[i][j]);
        }
    }
    const float* bp = bias + (bias_per_n ? n * C_ : 0);
#pragma unroll
    for (int i = 0; i < 8; ++i) {
        int co = co0 + coq + (i << 4);
        float bv = bp[co];
        float* yp = Y + (size_t)n * CL_ + (size_t)co * L_ + l0 + pxq;
#pragma unroll
        for (int j = 0; j < 8; ++j)
            yp[j << 4] = fmaxf(acc[i][j] + bv, 0.f);
    }
}

extern "C" void kernel_launch(void* const* d_in, const int* in_sizes, int n_in,
                              void* d_out, int out_size, void* d_ws, size_t ws_size,
                              hipStream_t stream)
{
    const float* feature = (const float*)d_in[0];
    const float* conv_w  = (const float*)d_in[1];
    const float* conv_b  = (const float*)d_in[2];
    const float* cent    = (const float*)d_in[3];
    const float* upfc_w  = (const float*)d_in[4];
    const float* upfc_b  = (const float*)d_in[5];
    const float* t1w     = (const float*)d_in[6];
    const float* t1b     = (const float*)d_in[7];
    const float* t2w     = (const float*)d_in[8];
    const float* t2b     = (const float*)d_in[9];

    float* ws    = (float*)d_ws;                 // same ~77 MB footprint as round 2
    float* rinv  = ws;                           // 65536
    float* sa    = rinv + 65536;                 // 2097152
    float* up    = sa + 2097152;                 // 131072
    float* upn   = up + 131072;                  // 131072
    float* ssum  = upn + 131072;                 // 512
    float* rowss = ssum + 512;                   // 512
    float* upvec = rowss + 512;                  // 4096
    float* t1up  = upvec + 4096;                 // 4096
    float* h     = t1up + 4096;                  // 16777216 floats (64 MB)
    // xnb (32 MB) + wb (144 KB) alias inside h: both fully consumed by
    // k_conv_mfma, which runs before k_gemm writes h.
    unsigned short* xnb = (unsigned short*)h;            // 16777216 ushorts
    unsigned short* wb  = xnb + 16777216;                // 73728 ushorts
    float* out   = (float*)d_out;

    hipMemsetAsync(up, 0, 131072 * sizeof(float), stream);
    k_prep     <<<2048, 256, 0, stream>>>(feature, rinv, xnb);
    k_wpack    <<<288,  256, 0, stream>>>(conv_w, wb);
    k_conv_mfma<<<512,  256, 0, stream>>>(xnb, wb, conv_b, sa);
    k_ssum     <<<512,  256, 0, stream>>>(sa, ssum);
    k_einsum   <<<512,  256, 0, stream>>>(feature, rinv, sa, up);
    k_rowfix   <<<512,  256, 0, stream>>>(up, ssum, cent, upn, rowss);
    k_fc       <<<64,   256, 0, stream>>>(upn, rowss, upfc_w, upfc_b, upvec);
    k_t1up     <<<16,   256, 0, stream>>>(upvec, t1w, t1b, t1up);
    k_gemm     <<<1024, 256, 0, stream>>>(feature, t1w, 512, t1up, 1, h);
    k_gemm     <<<1024, 256, 0, stream>>>(h,       t2w, 256, t2b, 0, out);
}

// Round 4
// 364.615 us; speedup vs baseline: 4.8013x; 1.9676x over previous
//
#include <hip/hip_runtime.h>
#include <cstdint>

#define N_ 16
#define C_ 256
#define H_ 64
#define W_ 64
#define L_ 4096          // H*W
#define K_ 32
#define CL_ (C_*L_)      // 1048576
#define KL_ (K_*L_)      // 131072
#define KC_ (K_*C_)      // 8192

typedef __attribute__((ext_vector_type(8))) short short8;   // 8 bf16 (4 VGPRs)
typedef __attribute__((ext_vector_type(4))) float f32x4;    // MFMA C/D frag

__device__ __forceinline__ unsigned short f2bf(float x) {   // RNE fp32->bf16
    unsigned int u = __float_as_uint(x);
    u += 0x7fffu + ((u >> 16) & 1u);
    return (unsigned short)(u >> 16);
}

// ---------- K1: fused rinv + xn(bf16) + raw feature(bf16), both transposed to (n,l,c) ----------
// grid: 16 n x 128 strips (32 l each) = 2048 blocks x 256 threads
__global__ __launch_bounds__(256) void k_prep(
    const float* __restrict__ f, float* __restrict__ rinv,
    unsigned short* __restrict__ xnb, unsigned short* __restrict__ fb)
{
    __shared__ float tile[256 * 34];            // [c][l], stride 34 (conflict-free)
    __shared__ float ssred[8 * 33];
    __shared__ float rbuf[32];
    int bid = blockIdx.x;
    int n = bid >> 7;
    int l0 = (bid & 127) << 5;
    int tid = threadIdx.x;
    int l = tid & 31, cb = tid >> 5;            // cb 0..7
    const float* fp = f + (size_t)n * CL_ + l0 + l;
    float ss = 0.f;
#pragma unroll
    for (int i = 0; i < 32; ++i) {
        int c = (cb << 5) + i;
        float v = fp[(size_t)c * L_];
        tile[c * 34 + l] = v;
        ss = fmaf(v, v, ss);
    }
    ssred[cb * 33 + l] = ss;
    __syncthreads();
    if (tid < 32) {
        float s = 0.f;
#pragma unroll
        for (int j = 0; j < 8; ++j) s += ssred[j * 33 + tid];
        float ri = 1.0f / fmaxf(sqrtf(s), 1e-12f);
        rinv[n * L_ + l0 + tid] = ri;
        rbuf[tid] = ri;
    }
    __syncthreads();
    float ri = rbuf[l];
    size_t rowoff = ((size_t)n * L_ + l0 + l) * C_ + (cb << 5);
    unsigned short* op  = xnb + rowoff;
    unsigned short* op2 = fb + rowoff;
#pragma unroll
    for (int g = 0; g < 4; ++g) {
        unsigned int pk[4], pr[4];
#pragma unroll
        for (int d = 0; d < 4; ++d) {
            int c = (cb << 5) + (g << 3) + (d << 1);
            float v0 = tile[c * 34 + l], v1 = tile[(c + 1) * 34 + l];
            pk[d] = (unsigned int)f2bf(v0 * ri) | ((unsigned int)f2bf(v1 * ri) << 16);
            pr[d] = (unsigned int)f2bf(v0)      | ((unsigned int)f2bf(v1) << 16);
        }
        *(uint4*)(op  + (g << 3)) = make_uint4(pk[0], pk[1], pk[2], pk[3]);
        *(uint4*)(op2 + (g << 3)) = make_uint4(pr[0], pr[1], pr[2], pr[3]);
    }
}

// ---------- K2: repack conv weights -> wb[t][k][c] bf16 ----------
__global__ __launch_bounds__(256) void k_wpack(const float* __restrict__ w, unsigned short* __restrict__ wb) {
    int i = blockIdx.x * 256 + threadIdx.x;     // 73728
    int t = i >> 13;
    int k = (i >> 8) & 31;
    int c = i & 255;
    wb[i] = f2bf(w[k * 2304 + c * 9 + t]);
}

// ---------- generic 256x256 weight pack (row stride in floats) ----------
__global__ __launch_bounds__(256) void k_wpack2(const float* __restrict__ w, int stride,
                                                unsigned short* __restrict__ wb) {
    int i = blockIdx.x * 256 + threadIdx.x;     // 65536
    int co = i >> 8, ci = i & 255;
    wb[i] = f2bf(w[(size_t)co * stride + ci]);
}

// ---------- K3: MFMA implicit-GEMM 3x3 conv + fused softmax over K ----------
__global__ __launch_bounds__(256) void k_conv_mfma(
    const unsigned short* __restrict__ xnb, const unsigned short* __restrict__ wb,
    const float* __restrict__ bias, float* __restrict__ sa)
{
    int bid = blockIdx.x;
    int n = bid >> 5;
    int y0 = (bid & 31) << 1;
    int wv = threadIdx.x >> 6, lane = threadIdx.x & 63;
    int y = y0 + (wv >> 1);
    int x0 = (wv & 1) << 5;                     // 0 or 32
    int px = lane & 15, quad = lane >> 4;
    const unsigned short* xb = xnb + (size_t)n * CL_;   // (l, c) bf16
    short8 zz = {0, 0, 0, 0, 0, 0, 0, 0};
    f32x4 acc[2][2];
#pragma unroll
    for (int pt = 0; pt < 2; ++pt)
#pragma unroll
        for (int m = 0; m < 2; ++m) acc[pt][m] = (f32x4){0.f, 0.f, 0.f, 0.f};

    for (int c0 = 0; c0 < 256; c0 += 32) {
        short8 a[9][2];
#pragma unroll
        for (int t = 0; t < 9; ++t)
#pragma unroll
            for (int m = 0; m < 2; ++m)
                a[t][m] = *(const short8*)(wb + t * 8192 + ((m << 4) + px) * 256 + c0 + (quad << 3));
#pragma unroll
        for (int t = 0; t < 9; ++t) {
            int dy = t / 3 - 1, dx = t % 3 - 1;
            int yy = y + dy;
            if ((unsigned)yy < 64u) {           // wave-uniform row validity
#pragma unroll
                for (int pt = 0; pt < 2; ++pt) {
                    int xx = x0 + (pt << 4) + px + dx;
                    bool okx = (unsigned)xx < 64u;
                    int xs = okx ? xx : 0;
                    short8 b = *(const short8*)(xb + ((size_t)(yy << 6) + xs) * 256 + c0 + (quad << 3));
                    if (!okx) b = zz;           // zero-padding at x edges
                    acc[pt][0] = __builtin_amdgcn_mfma_f32_16x16x32_bf16(a[t][0], b, acc[pt][0], 0, 0, 0);
                    acc[pt][1] = __builtin_amdgcn_mfma_f32_16x16x32_bf16(a[t][1], b, acc[pt][1], 0, 0, 0);
                }
            }
        }
    }
    float4 b0 = *(const float4*)(bias + (quad << 2));
    float4 b1 = *(const float4*)(bias + 16 + (quad << 2));
#pragma unroll
    for (int pt = 0; pt < 2; ++pt) {
        float v[8];
        v[0] = acc[pt][0][0] + b0.x; v[1] = acc[pt][0][1] + b0.y;
        v[2] = acc[pt][0][2] + b0.z; v[3] = acc[pt][0][3] + b0.w;
        v[4] = acc[pt][1][0] + b1.x; v[5] = acc[pt][1][1] + b1.y;
        v[6] = acc[pt][1][2] + b1.z; v[7] = acc[pt][1][3] + b1.w;
        float mx = v[0];
#pragma unroll
        for (int r = 1; r < 8; ++r) mx = fmaxf(mx, v[r]);
        mx = fmaxf(mx, __shfl_xor(mx, 16));
        mx = fmaxf(mx, __shfl_xor(mx, 32));
        float s = 0.f;
#pragma unroll
        for (int r = 0; r < 8; ++r) { v[r] = __expf(v[r] - mx); s += v[r]; }
        s += __shfl_xor(s, 16);
        s += __shfl_xor(s, 32);
        float rs = 1.0f / s;
        int l = (y << 6) + x0 + (pt << 4) + px;
        float* sp = sa + (size_t)n * KL_ + l;
#pragma unroll
        for (int r = 0; r < 4; ++r) {
            sp[(size_t)((quad << 2) + r) * L_] = v[r] * rs;
            sp[(size_t)(16 + (quad << 2) + r) * L_] = v[4 + r] * rs;
        }
    }
}

// ---------- K4: ssum[n,k] = sum_l sa[n,k,l] ----------
__global__ __launch_bounds__(256) void k_ssum(const float* __restrict__ sa, float* __restrict__ ssum) {
    __shared__ float red[256];
    int bid = blockIdx.x;                       // n*K + k
    const float* sp = sa + (size_t)bid * L_;
    float s = 0.f;
    for (int m = 0; m < 16; ++m) s += sp[threadIdx.x + (m << 8)];
    red[threadIdx.x] = s; __syncthreads();
    for (int st = 128; st > 0; st >>= 1) {
        if (threadIdx.x < st) red[threadIdx.x] += red[threadIdx.x + st];
        __syncthreads();
    }
    if (threadIdx.x == 0) ssum[bid] = red[0];
}

// ---------- K5: up[n,k,c] += sum_l sa[n,k,l] * xn[n,c,l] ----------
__global__ __launch_bounds__(256) void k_einsum(
    const float* __restrict__ f, const float* __restrict__ rinv,
    const float* __restrict__ sa, float* __restrict__ up)
{
    __shared__ float xn_s[C_ * 33];
    __shared__ float sa_s[K_ * 32];
    int bid = blockIdx.x;                       // 512
    int n = bid >> 5;
    int l0 = (bid & 31) << 7;
    int tid = threadIdx.x;
    int kq = tid >> 5, cq = tid & 31;
    float acc[4][8];
#pragma unroll
    for (int i = 0; i < 4; ++i)
#pragma unroll
        for (int j = 0; j < 8; ++j) acc[i][j] = 0.f;

    for (int ch = 0; ch < 4; ++ch) {
        int lc = l0 + (ch << 5);
        __syncthreads();
        {
            int crow = tid >> 3, lq = (tid & 7) << 2;
#pragma unroll
            for (int p = 0; p < 8; ++p) {
                int c = (p << 5) + crow;
                float4 f4 = *(const float4*)(f + (size_t)n * CL_ + (size_t)c * L_ + lc + lq);
                float4 r4 = *(const float4*)(rinv + n * L_ + lc + lq);
                float* d = xn_s + c * 33 + lq;
                d[0] = f4.x * r4.x; d[1] = f4.y * r4.y; d[2] = f4.z * r4.z; d[3] = f4.w * r4.w;
            }
        }
        {
            int k = tid >> 3, lq = (tid & 7) << 2;
            float4 a4 = *(const float4*)(sa + (size_t)n * KL_ + (size_t)k * L_ + lc + lq);
            *(float4*)(sa_s + (k << 5) + lq) = a4;
        }
        __syncthreads();
#pragma unroll 4
        for (int l = 0; l < 32; ++l) {
            float sv[4], xv[8];
#pragma unroll
            for (int i = 0; i < 4; ++i) sv[i] = sa_s[((kq << 2) + i) * 32 + l];
#pragma unroll
            for (int j = 0; j < 8; ++j) xv[j] = xn_s[(cq + (j << 5)) * 33 + l];
#pragma unroll
            for (int i = 0; i < 4; ++i)
#pragma unroll
                for (int j = 0; j < 8; ++j) acc[i][j] = fmaf(sv[i], xv[j], acc[i][j]);
        }
    }
    float* upp = up + (size_t)n * KC_;
#pragma unroll
    for (int i = 0; i < 4; ++i)
#pragma unroll
        for (int j = 0; j < 8; ++j)
            atomicAdd(upp + ((kq << 2) + i) * C_ + cq + (j << 5), acc[i][j]);
}

// ---------- K6: subtract centroid term, l2norm rows, record row sumsq ----------
__global__ __launch_bounds__(256) void k_rowfix(
    const float* __restrict__ up, const float* __restrict__ ssum,
    const float* __restrict__ cent, float* __restrict__ upn, float* __restrict__ rowss)
{
    __shared__ float red[256];
    int bid = blockIdx.x;                       // n*K + k
    int k = bid & 31;
    float sv = ssum[bid];
    float v = up[(size_t)bid * C_ + threadIdx.x] - sv * cent[k * C_ + threadIdx.x];
    red[threadIdx.x] = v * v; __syncthreads();
    for (int st = 128; st > 0; st >>= 1) {
        if (threadIdx.x < st) red[threadIdx.x] += red[threadIdx.x + st];
        __syncthreads();
    }
    float ss = red[0];
    float ri = 1.0f / fmaxf(sqrtf(ss), 1e-12f);
    upn[(size_t)bid * C_ + threadIdx.x] = v * ri;
    if (threadIdx.x == 0) rowss[bid] = ss * ri * ri;
}

// ---------- K7: global l2norm + FC, one block per output channel c ----------
__global__ __launch_bounds__(256) void k_fc(
    const float* __restrict__ upn, const float* __restrict__ rowss,
    const float* __restrict__ w, const float* __restrict__ b,
    float* __restrict__ upvec)
{
    __shared__ float rnb[16];
    __shared__ float red[16][5];
    int c = blockIdx.x;                         // 256
    int tid = threadIdx.x;
    int wv = tid >> 6, lane = tid & 63;
    if (tid < 16) {
        float ts = 0.f;
#pragma unroll
        for (int k = 0; k < K_; ++k) ts += rowss[(tid << 5) + k];
        rnb[tid] = 1.0f / fmaxf(sqrtf(ts), 1e-12f);
    }
    float acc[16];
#pragma unroll
    for (int n = 0; n < 16; ++n) acc[n] = 0.f;
    const float* wr = w + (size_t)c * KC_;
#pragma unroll
    for (int g = 0; g < 8; ++g) {
        int kc = (g << 10) + (tid << 2);
        float4 w4 = *(const float4*)(wr + kc);
#pragma unroll
        for (int n = 0; n < 16; ++n) {
            float4 u4 = *(const float4*)(upn + n * KC_ + kc);
            acc[n] += w4.x * u4.x + w4.y * u4.y + w4.z * u4.z + w4.w * u4.w;
        }
    }
#pragma unroll
    for (int n = 0; n < 16; ++n) {
        float a = acc[n];
#pragma unroll
        for (int s = 1; s < 64; s <<= 1) a += __shfl_xor(a, s);
        if (lane == 0) red[n][wv] = a;
    }
    __syncthreads();
    if (tid < 16) {
        float v = red[tid][0] + red[tid][1] + red[tid][2] + red[tid][3];
        upvec[tid * C_ + c] = v * rnb[tid] + b[c];
    }
}

// ---------- K8: t1up[n,co] = t1_w[co,256:512] . upvec[n,:] + t1_b[co], one block per co ----------
__global__ __launch_bounds__(256) void k_t1up(
    const float* __restrict__ upvec, const float* __restrict__ t1w,
    const float* __restrict__ t1b, float* __restrict__ t1up)
{
    __shared__ float wld[256];
    int co = blockIdx.x;                        // 256
    int tid = threadIdx.x;
    wld[tid] = t1w[(size_t)co * 512 + 256 + tid];
    __syncthreads();
    int n = tid >> 4, s = tid & 15;
    float a = 0.f;
#pragma unroll
    for (int i = 0; i < 16; ++i)
        a += wld[s + (i << 4)] * upvec[n * C_ + s + (i << 4)];
#pragma unroll
    for (int st = 1; st < 16; st <<= 1) a += __shfl_xor(a, st);
    if (s == 0) t1up[n * C_ + co] = a + t1b[co];
}

// ---------- K9: MFMA gemm1: hb[n,l,co] = bf16(relu(fb[n,l,:]·t1wb[co,:] + t1up[n,co])) ----------
__global__ __launch_bounds__(256) void k_gemm1(
    const unsigned short* __restrict__ fb, const unsigned short* __restrict__ wb,
    const float* __restrict__ t1up, unsigned short* __restrict__ hb)
{
    int bid = blockIdx.x;                       // 1024 = n(16) x px_b(32) x co_b(2)
    int co_b = bid & 1, px_b = (bid >> 1) & 31, n = bid >> 6;
    int wv = threadIdx.x >> 6, lane = threadIdx.x & 63;
    int r = lane & 15, quad = lane >> 4;
    int px0 = (px_b << 7) + ((wv >> 1) << 6);
    int co0 = (co_b << 7) + ((wv & 1) << 6);
    const unsigned short* xrow = fb + ((size_t)n * L_ + px0) * C_;
    f32x4 acc[4][4];
#pragma unroll
    for (int i = 0; i < 4; ++i)
#pragma unroll
        for (int j = 0; j < 4; ++j) acc[i][j] = (f32x4){0.f, 0.f, 0.f, 0.f};
#pragma unroll 2
    for (int c0 = 0; c0 < 256; c0 += 32) {
        short8 A[4], B[4];
#pragma unroll
        for (int t = 0; t < 4; ++t)
            A[t] = *(const short8*)(wb + (size_t)(co0 + (t << 4) + r) * C_ + c0 + (quad << 3));
#pragma unroll
        for (int t = 0; t < 4; ++t)
            B[t] = *(const short8*)(xrow + (size_t)((t << 4) + r) * C_ + c0 + (quad << 3));
#pragma unroll
        for (int pxt = 0; pxt < 4; ++pxt)
#pragma unroll
            for (int cot = 0; cot < 4; ++cot)
                acc[pxt][cot] = __builtin_amdgcn_mfma_f32_16x16x32_bf16(A[cot], B[pxt], acc[pxt][cot], 0, 0, 0);
    }
#pragma unroll
    for (int pxt = 0; pxt < 4; ++pxt) {
        int px = px0 + (pxt << 4) + r;
        unsigned short* orow = hb + ((size_t)n * L_ + px) * C_;
#pragma unroll
        for (int cot = 0; cot < 4; ++cot) {
            int cb = co0 + (cot << 4) + (quad << 2);
            float4 bb = *(const float4*)(t1up + n * C_ + cb);
            unsigned int p0 = (unsigned int)f2bf(fmaxf(acc[pxt][cot][0] + bb.x, 0.f)) |
                              ((unsigned int)f2bf(fmaxf(acc[pxt][cot][1] + bb.y, 0.f)) << 16);
            unsigned int p1 = (unsigned int)f2bf(fmaxf(acc[pxt][cot][2] + bb.z, 0.f)) |
                              ((unsigned int)f2bf(fmaxf(acc[pxt][cot][3] + bb.w, 0.f)) << 16);
            *(uint2*)(orow + cb) = make_uint2(p0, p1);
        }
    }
}

// ---------- K10: MFMA gemm2: out[n,co,l] = relu(hb[n,l,:]·t2wb[co,:] + t2b[co]) ----------
__global__ __launch_bounds__(256) void k_gemm2(
    const unsigned short* __restrict__ hb, const unsigned short* __restrict__ wb,
    const float* __restrict__ t2b, float* __restrict__ out)
{
    int bid = blockIdx.x;                       // 1024
    int co_b = bid & 1, px_b = (bid >> 1) & 31, n = bid >> 6;
    int wv = threadIdx.x >> 6, lane = threadIdx.x & 63;
    int r = lane & 15, quad = lane >> 4;
    int px0 = (px_b << 7) + ((wv >> 1) << 6);
    int co0 = (co_b << 7) + ((wv & 1) << 6);
    const unsigned short* xrow = hb + ((size_t)n * L_ + px0) * C_;
    f32x4 acc[4][4];
#pragma unroll
    for (int i = 0; i < 4; ++i)
#pragma unroll
        for (int j = 0; j < 4; ++j) acc[i][j] = (f32x4){0.f, 0.f, 0.f, 0.f};
#pragma unroll 2
    for (int c0 = 0; c0 < 256; c0 += 32) {
        short8 A[4], B[4];
#pragma unroll
        for (int t = 0; t < 4; ++t)
            A[t] = *(const short8*)(wb + (size_t)(co0 + (t << 4) + r) * C_ + c0 + (quad << 3));
#pragma unroll
        for (int t = 0; t < 4; ++t)
            B[t] = *(const short8*)(xrow + (size_t)((t << 4) + r) * C_ + c0 + (quad << 3));
#pragma unroll
        for (int pxt = 0; pxt < 4; ++pxt)
#pragma unroll
            for (int cot = 0; cot < 4; ++cot)
                acc[pxt][cot] = __builtin_amdgcn_mfma_f32_16x16x32_bf16(A[cot], B[pxt], acc[pxt][cot], 0, 0, 0);
    }
#pragma unroll
    for (int pxt = 0; pxt < 4; ++pxt) {
        int px = px0 + (pxt << 4) + r;
#pragma unroll
        for (int cot = 0; cot < 4; ++cot) {
            int cb = co0 + (cot << 4) + (quad << 2);
            float4 bb = *(const float4*)(t2b + cb);
            out[((size_t)n * C_ + cb + 0) * L_ + px] = fmaxf(acc[pxt][cot][0] + bb.x, 0.f);
            out[((size_t)n * C_ + cb + 1) * L_ + px] = fmaxf(acc[pxt][cot][1] + bb.y, 0.f);
            out[((size_t)n * C_ + cb + 2) * L_ + px] = fmaxf(acc[pxt][cot][2] + bb.z, 0.f);
            out[((size_t)n * C_ + cb + 3) * L_ + px] = fmaxf(acc[pxt][cot][3] + bb.w, 0.f);
        }
    }
}

extern "C" void kernel_launch(void* const* d_in, const int* in_sizes, int n_in,
                              void* d_out, int out_size, void* d_ws, size_t ws_size,
                              hipStream_t stream)
{
    const float* feature = (const float*)d_in[0];
    const float* conv_w  = (const float*)d_in[1];
    const float* conv_b  = (const float*)d_in[2];
    const float* cent    = (const float*)d_in[3];
    const float* upfc_w  = (const float*)d_in[4];
    const float* upfc_b  = (const float*)d_in[5];
    const float* t1w     = (const float*)d_in[6];
    const float* t1b     = (const float*)d_in[7];
    const float* t2w     = (const float*)d_in[8];
    const float* t2b     = (const float*)d_in[9];

    float* ws = (float*)d_ws;                    // 76.85 MB total — same as proven footprint
    unsigned short* fb  = (unsigned short*)ws;           // 16777216 us (32 MB)
    unsigned short* xnb = fb + 16777216;                 // 16777216 us (32 MB)
    unsigned short* hb  = xnb;                           // alias: xnb dead after k_conv_mfma
    float* rest  = ws + 8388608 + 8388608;
    float* rinv  = rest;                         // 65536
    float* sa    = rinv + 65536;                 // 2097152 (8 MB)
    float* up    = sa + 2097152;                 // 131072
    float* upn   = up + 131072;                  // 131072
    float* ssum  = upn + 131072;                 // 512
    float* rowss = ssum + 512;                   // 512
    float* upvec = rowss + 512;                  // 4096
    float* t1up  = upvec + 4096;                 // 4096
    // conv wb aliases upn (upn written by k_rowfix AFTER conv is done)
    unsigned short* wbconv = (unsigned short*)upn;       // 73728 us <= 131072 floats
    // t1wb/t2wb alias sa (sa dead after k_einsum; packed after k_rowfix)
    unsigned short* t1wb = (unsigned short*)sa;          // 65536 us
    unsigned short* t2wb = t1wb + 65536;                 // 65536 us
    float* out = (float*)d_out;

    hipMemsetAsync(up, 0, 131072 * sizeof(float), stream);
    k_prep     <<<2048, 256, 0, stream>>>(feature, rinv, xnb, fb);
    k_wpack    <<<288,  256, 0, stream>>>(conv_w, wbconv);
    k_conv_mfma<<<512,  256, 0, stream>>>(xnb, wbconv, conv_b, sa);
    k_ssum     <<<512,  256, 0, stream>>>(sa, ssum);
    k_einsum   <<<512,  256, 0, stream>>>(feature, rinv, sa, up);
    k_rowfix   <<<512,  256, 0, stream>>>(up, ssum, cent, upn, rowss);
    k_wpack2   <<<256,  256, 0, stream>>>(t1w, 512, t1wb);
    k_wpack2   <<<256,  256, 0, stream>>>(t2w, 256, t2wb);
    k_fc       <<<256,  256, 0, stream>>>(upn, rowss, upfc_w, upfc_b, upvec);
    k_t1up     <<<256,  256, 0, stream>>>(upvec, t1w, t1b, t1up);
    k_gemm1    <<<1024, 256, 0, stream>>>(fb, t1wb, t1up, hb);
    k_gemm2    <<<1024, 256, 0, stream>>>(hb, t2wb, t2b, out);
}

// Round 5
// 360.579 us; speedup vs baseline: 4.8551x; 1.0112x over previous
//
#include <hip/hip_runtime.h>
#include <cstdint>

#define N_ 16
#define C_ 256
#define H_ 64
#define W_ 64
#define L_ 4096          // H*W
#define K_ 32
#define CL_ (C_*L_)      // 1048576
#define KL_ (K_*L_)      // 131072
#define KC_ (K_*C_)      // 8192

typedef __attribute__((ext_vector_type(8))) short short8;   // 8 bf16 (4 VGPRs)
typedef __attribute__((ext_vector_type(4))) float f32x4;    // MFMA C/D frag

__device__ __forceinline__ unsigned short f2bf(float x) {   // RNE fp32->bf16
    unsigned int u = __float_as_uint(x);
    u += 0x7fffu + ((u >> 16) & 1u);
    return (unsigned short)(u >> 16);
}

// ---------- K1: fused rinv + xn(bf16) transposed to (n,l,c) ----------
__global__ __launch_bounds__(256) void k_prep(
    const float* __restrict__ f, float* __restrict__ rinv,
    unsigned short* __restrict__ xnb)
{
    __shared__ float tile[256 * 34];            // [c][l], stride 34 (conflict-free)
    __shared__ float ssred[8 * 33];
    __shared__ float rbuf[32];
    int bid = blockIdx.x;
    int n = bid >> 7;
    int l0 = (bid & 127) << 5;
    int tid = threadIdx.x;
    int l = tid & 31, cb = tid >> 5;            // cb 0..7
    const float* fp = f + (size_t)n * CL_ + l0 + l;
    float ss = 0.f;
#pragma unroll
    for (int i = 0; i < 32; ++i) {
        int c = (cb << 5) + i;
        float v = fp[(size_t)c * L_];
        tile[c * 34 + l] = v;
        ss = fmaf(v, v, ss);
    }
    ssred[cb * 33 + l] = ss;
    __syncthreads();
    if (tid < 32) {
        float s = 0.f;
#pragma unroll
        for (int j = 0; j < 8; ++j) s += ssred[j * 33 + tid];
        float ri = 1.0f / fmaxf(sqrtf(s), 1e-12f);
        rinv[n * L_ + l0 + tid] = ri;
        rbuf[tid] = ri;
    }
    __syncthreads();
    float ri = rbuf[l];
    unsigned short* op = xnb + ((size_t)n * L_ + l0 + l) * C_ + (cb << 5);
#pragma unroll
    for (int g = 0; g < 4; ++g) {
        unsigned int pk[4];
#pragma unroll
        for (int d = 0; d < 4; ++d) {
            int c = (cb << 5) + (g << 3) + (d << 1);
            pk[d] = (unsigned int)f2bf(tile[c * 34 + l] * ri) |
                    ((unsigned int)f2bf(tile[(c + 1) * 34 + l] * ri) << 16);
        }
        *(uint4*)(op + (g << 3)) = make_uint4(pk[0], pk[1], pk[2], pk[3]);
    }
}

// ---------- K2: repack conv weights -> wb[t][k][c] bf16 ----------
__global__ __launch_bounds__(256) void k_wpack(const float* __restrict__ w, unsigned short* __restrict__ wb) {
    int i = blockIdx.x * 256 + threadIdx.x;     // 73728
    int t = i >> 13;
    int k = (i >> 8) & 31;
    int c = i & 255;
    wb[i] = f2bf(w[k * 2304 + c * 9 + t]);
}

// ---------- generic 256x256 weight pack (row stride in floats) ----------
__global__ __launch_bounds__(256) void k_wpack2(const float* __restrict__ w, int stride,
                                                unsigned short* __restrict__ wb) {
    int i = blockIdx.x * 256 + threadIdx.x;     // 65536
    int co = i >> 8, ci = i & 255;
    wb[i] = f2bf(w[(size_t)co * stride + ci]);
}

// ---------- K3: LDS-staged MFMA 3x3 conv + fused softmax over K ----------
// grid: 16 n x 64 rows = 1024 blocks x 256 threads; wave w owns px = w*16..w*16+15
__global__ __launch_bounds__(256) void k_conv(
    const unsigned short* __restrict__ xnb, const unsigned short* __restrict__ wb,
    const float* __restrict__ bias, float* __restrict__ sa)
{
    __shared__ __align__(16) unsigned short lsB[3 * 66 * 32];   // 25344 B, zero-padded halo
    int bid = blockIdx.x;
    int n = bid >> 6, y = bid & 63;
    int tid = threadIdx.x;
    int wv = tid >> 6, lane = tid & 63;
    int r = lane & 15, quad = lane >> 4;
    int pxw = (wv << 4) + r;                    // this lane's output x
    const unsigned short* xb = xnb + (size_t)n * CL_;
    f32x4 acc0 = (f32x4){0.f, 0.f, 0.f, 0.f};
    f32x4 acc1 = (f32x4){0.f, 0.f, 0.f, 0.f};

    for (int c0 = 0; c0 < 256; c0 += 32) {
        __syncthreads();
        for (int j = tid; j < 792; j += 256) {  // 3 rows x 66 px x 4 quads
            int row = j / 264;
            int rem = j - row * 264;
            int px = rem >> 2, q = rem & 3;
            int yy = y + row - 1, xx = px - 1;
            uint4 v = make_uint4(0, 0, 0, 0);
            if ((unsigned)yy < 64u && (unsigned)xx < 64u)
                v = *(const uint4*)(xb + (((size_t)(yy << 6) + xx) << 8) + c0 + (q << 3));
            *(uint4*)(lsB + (row * 66 + px) * 32 + (q << 3)) = v;
        }
        __syncthreads();
#pragma unroll
        for (int t = 0; t < 9; ++t) {
            int dy = t / 3, dx = t % 3;         // LDS slot indices (halo built in)
            short8 B = *(const short8*)(lsB + (dy * 66 + pxw + dx) * 32 + (quad << 3));
            short8 A0 = *(const short8*)(wb + t * 8192 + r * 256 + c0 + (quad << 3));
            short8 A1 = *(const short8*)(wb + t * 8192 + (16 + r) * 256 + c0 + (quad << 3));
            acc0 = __builtin_amdgcn_mfma_f32_16x16x32_bf16(A0, B, acc0, 0, 0, 0);
            acc1 = __builtin_amdgcn_mfma_f32_16x16x32_bf16(A1, B, acc1, 0, 0, 0);
        }
    }
    // bias + softmax over k (32 values per px: 4 quads x 8 regs)
    float4 b0 = *(const float4*)(bias + (quad << 2));
    float4 b1 = *(const float4*)(bias + 16 + (quad << 2));
    float v[8];
    v[0] = acc0[0] + b0.x; v[1] = acc0[1] + b0.y; v[2] = acc0[2] + b0.z; v[3] = acc0[3] + b0.w;
    v[4] = acc1[0] + b1.x; v[5] = acc1[1] + b1.y; v[6] = acc1[2] + b1.z; v[7] = acc1[3] + b1.w;
    float mx = v[0];
#pragma unroll
    for (int j = 1; j < 8; ++j) mx = fmaxf(mx, v[j]);
    mx = fmaxf(mx, __shfl_xor(mx, 16));
    mx = fmaxf(mx, __shfl_xor(mx, 32));
    float s = 0.f;
#pragma unroll
    for (int j = 0; j < 8; ++j) { v[j] = __expf(v[j] - mx); s += v[j]; }
    s += __shfl_xor(s, 16);
    s += __shfl_xor(s, 32);
    float rs = 1.0f / s;
    int l = (y << 6) + pxw;
    float* sp = sa + (size_t)n * KL_ + l;
#pragma unroll
    for (int j = 0; j < 4; ++j) {
        sp[(size_t)((quad << 2) + j) * L_] = v[j] * rs;
        sp[(size_t)(16 + (quad << 2) + j) * L_] = v[4 + j] * rs;
    }
}

// ---------- K4: ssum[n,k] = sum_l sa[n,k,l] ----------
__global__ __launch_bounds__(256) void k_ssum(const float* __restrict__ sa, float* __restrict__ ssum) {
    __shared__ float red[256];
    int bid = blockIdx.x;                       // n*K + k
    const float* sp = sa + (size_t)bid * L_;
    float s = 0.f;
    for (int m = 0; m < 16; ++m) s += sp[threadIdx.x + (m << 8)];
    red[threadIdx.x] = s; __syncthreads();
    for (int st = 128; st > 0; st >>= 1) {
        if (threadIdx.x < st) red[threadIdx.x] += red[threadIdx.x + st];
        __syncthreads();
    }
    if (threadIdx.x == 0) ssum[bid] = red[0];
}

// ---------- K5: up[n,k,c] += sum_l sa[n,k,l] * xn[n,c,l] ----------
__global__ __launch_bounds__(256) void k_einsum(
    const float* __restrict__ f, const float* __restrict__ rinv,
    const float* __restrict__ sa, float* __restrict__ up)
{
    __shared__ float xn_s[C_ * 33];
    __shared__ float sa_s[K_ * 32];
    int bid = blockIdx.x;                       // 512
    int n = bid >> 5;
    int l0 = (bid & 31) << 7;
    int tid = threadIdx.x;
    int kq = tid >> 5, cq = tid & 31;
    float acc[4][8];
#pragma unroll
    for (int i = 0; i < 4; ++i)
#pragma unroll
        for (int j = 0; j < 8; ++j) acc[i][j] = 0.f;

    for (int ch = 0; ch < 4; ++ch) {
        int lc = l0 + (ch << 5);
        __syncthreads();
        {
            int crow = tid >> 3, lq = (tid & 7) << 2;
#pragma unroll
            for (int p = 0; p < 8; ++p) {
                int c = (p << 5) + crow;
                float4 f4 = *(const float4*)(f + (size_t)n * CL_ + (size_t)c * L_ + lc + lq);
                float4 r4 = *(const float4*)(rinv + n * L_ + lc + lq);
                float* d = xn_s + c * 33 + lq;
                d[0] = f4.x * r4.x; d[1] = f4.y * r4.y; d[2] = f4.z * r4.z; d[3] = f4.w * r4.w;
            }
        }
        {
            int k = tid >> 3, lq = (tid & 7) << 2;
            float4 a4 = *(const float4*)(sa + (size_t)n * KL_ + (size_t)k * L_ + lc + lq);
            *(float4*)(sa_s + (k << 5) + lq) = a4;
        }
        __syncthreads();
#pragma unroll 4
        for (int l = 0; l < 32; ++l) {
            float sv[4], xv[8];
#pragma unroll
            for (int i = 0; i < 4; ++i) sv[i] = sa_s[((kq << 2) + i) * 32 + l];
#pragma unroll
            for (int j = 0; j < 8; ++j) xv[j] = xn_s[(cq + (j << 5)) * 33 + l];
#pragma unroll
            for (int i = 0; i < 4; ++i)
#pragma unroll
                for (int j = 0; j < 8; ++j) acc[i][j] = fmaf(sv[i], xv[j], acc[i][j]);
        }
    }
    float* upp = up + (size_t)n * KC_;
#pragma unroll
    for (int i = 0; i < 4; ++i)
#pragma unroll
        for (int j = 0; j < 8; ++j)
            atomicAdd(upp + ((kq << 2) + i) * C_ + cq + (j << 5), acc[i][j]);
}

// ---------- K6: subtract centroid term, l2norm rows, record row sumsq ----------
__global__ __launch_bounds__(256) void k_rowfix(
    const float* __restrict__ up, const float* __restrict__ ssum,
    const float* __restrict__ cent, float* __restrict__ upn, float* __restrict__ rowss)
{
    __shared__ float red[256];
    int bid = blockIdx.x;                       // n*K + k
    int k = bid & 31;
    float sv = ssum[bid];
    float v = up[(size_t)bid * C_ + threadIdx.x] - sv * cent[k * C_ + threadIdx.x];
    red[threadIdx.x] = v * v; __syncthreads();
    for (int st = 128; st > 0; st >>= 1) {
        if (threadIdx.x < st) red[threadIdx.x] += red[threadIdx.x + st];
        __syncthreads();
    }
    float ss = red[0];
    float ri = 1.0f / fmaxf(sqrtf(ss), 1e-12f);
    upn[(size_t)bid * C_ + threadIdx.x] = v * ri;
    if (threadIdx.x == 0) rowss[bid] = ss * ri * ri;
}

// ---------- K7: global l2norm + FC, one block per output channel c ----------
__global__ __launch_bounds__(256) void k_fc(
    const float* __restrict__ upn, const float* __restrict__ rowss,
    const float* __restrict__ w, const float* __restrict__ b,
    float* __restrict__ upvec)
{
    __shared__ float rnb[16];
    __shared__ float red[16][5];
    int c = blockIdx.x;                         // 256
    int tid = threadIdx.x;
    int wv = tid >> 6, lane = tid & 63;
    if (tid < 16) {
        float ts = 0.f;
#pragma unroll
        for (int k = 0; k < K_; ++k) ts += rowss[(tid << 5) + k];
        rnb[tid] = 1.0f / fmaxf(sqrtf(ts), 1e-12f);
    }
    float acc[16];
#pragma unroll
    for (int n = 0; n < 16; ++n) acc[n] = 0.f;
    const float* wr = w + (size_t)c * KC_;
#pragma unroll
    for (int g = 0; g < 8; ++g) {
        int kc = (g << 10) + (tid << 2);
        float4 w4 = *(const float4*)(wr + kc);
#pragma unroll
        for (int n = 0; n < 16; ++n) {
            float4 u4 = *(const float4*)(upn + n * KC_ + kc);
            acc[n] += w4.x * u4.x + w4.y * u4.y + w4.z * u4.z + w4.w * u4.w;
        }
    }
#pragma unroll
    for (int n = 0; n < 16; ++n) {
        float a = acc[n];
#pragma unroll
        for (int s = 1; s < 64; s <<= 1) a += __shfl_xor(a, s);
        if (lane == 0) red[n][wv] = a;
    }
    __syncthreads();
    if (tid < 16) {
        float v = red[tid][0] + red[tid][1] + red[tid][2] + red[tid][3];
        upvec[tid * C_ + c] = v * rnb[tid] + b[c];
    }
}

// ---------- K8: t1up[n,co] = t1_w[co,256:512] . upvec[n,:] + t1_b[co] ----------
__global__ __launch_bounds__(256) void k_t1up(
    const float* __restrict__ upvec, const float* __restrict__ t1w,
    const float* __restrict__ t1b, float* __restrict__ t1up)
{
    __shared__ float wld[256];
    int co = blockIdx.x;                        // 256
    int tid = threadIdx.x;
    wld[tid] = t1w[(size_t)co * 512 + 256 + tid];
    __syncthreads();
    int n = tid >> 4, s = tid & 15;
    float a = 0.f;
#pragma unroll
    for (int i = 0; i < 16; ++i)
        a += wld[s + (i << 4)] * upvec[n * C_ + s + (i << 4)];
#pragma unroll
    for (int st = 1; st < 16; st <<= 1) a += __shfl_xor(a, st);
    if (s == 0) t1up[n * C_ + co] = a + t1b[co];
}

// ---------- K9: MFMA gemm1, LDS-staged B from fp32 feature ----------
// hb[n,l,co] = bf16(relu(f[n,:,l]·t1wb[co,:] + t1up[n,co]))
__global__ __launch_bounds__(256) void k_gemm1(
    const float* __restrict__ f, const unsigned short* __restrict__ wb,
    const float* __restrict__ t1up, unsigned short* __restrict__ hb)
{
    __shared__ __align__(16) unsigned int lsB[2048];    // 128 px x 32 c bf16 (8 KB)
    int bid = blockIdx.x;                       // 1024 = n(16) x px_b(32) x co_b(2)
    int co_b = bid & 1, px_b = (bid >> 1) & 31, n = bid >> 6;
    int l0 = px_b << 7;
    int tid = threadIdx.x;
    int wv = tid >> 6, lane = tid & 63;
    int r = lane & 15, quad = lane >> 4;
    int pxl = (wv >> 1) << 6;                   // block-local px base for wave
    int co0 = (co_b << 7) + ((wv & 1) << 6);
    const float* fb_ = f + (size_t)n * CL_ + l0;
    f32x4 acc[4][4];
#pragma unroll
    for (int i = 0; i < 4; ++i)
#pragma unroll
        for (int j = 0; j < 4; ++j) acc[i][j] = (f32x4){0.f, 0.f, 0.f, 0.f};

    for (int c0 = 0; c0 < 256; c0 += 32) {
        __syncthreads();
        for (int u = tid; u < 512; u += 256) {  // 16 c-pairs x 32 px-quads
            int c2 = u & 15, pxg = u >> 4;
            const float* s0 = fb_ + (size_t)(c0 + (c2 << 1)) * L_ + (pxg << 2);
            float4 a = *(const float4*)s0;
            float4 b = *(const float4*)(s0 + L_);
            int base = (pxg << 6) + c2;         // uint idx = px*16 + c2
            lsB[base]      = (unsigned int)f2bf(a.x) | ((unsigned int)f2bf(b.x) << 16);
            lsB[base + 16] = (unsigned int)f2bf(a.y) | ((unsigned int)f2bf(b.y) << 16);
            lsB[base + 32] = (unsigned int)f2bf(a.z) | ((unsigned int)f2bf(b.z) << 16);
            lsB[base + 48] = (unsigned int)f2bf(a.w) | ((unsigned int)f2bf(b.w) << 16);
        }
        __syncthreads();
        short8 A[4], B[4];
#pragma unroll
        for (int t = 0; t < 4; ++t)
            A[t] = *(const short8*)(wb + (size_t)(co0 + (t << 4) + r) * C_ + c0 + (quad << 3));
#pragma unroll
        for (int t = 0; t < 4; ++t)
            B[t] = *(const short8*)((const unsigned short*)lsB + ((pxl + (t << 4) + r) << 5) + (quad << 3));
#pragma unroll
        for (int pxt = 0; pxt < 4; ++pxt)
#pragma unroll
            for (int cot = 0; cot < 4; ++cot)
                acc[pxt][cot] = __builtin_amdgcn_mfma_f32_16x16x32_bf16(A[cot], B[pxt], acc[pxt][cot], 0, 0, 0);
    }
#pragma unroll
    for (int pxt = 0; pxt < 4; ++pxt) {
        int px = l0 + pxl + (pxt << 4) + r;
        unsigned short* orow = hb + ((size_t)n * L_ + px) * C_;
#pragma unroll
        for (int cot = 0; cot < 4; ++cot) {
            int cb = co0 + (cot << 4) + (quad << 2);
            float4 bb = *(const float4*)(t1up + n * C_ + cb);
            unsigned int p0 = (unsigned int)f2bf(fmaxf(acc[pxt][cot][0] + bb.x, 0.f)) |
                              ((unsigned int)f2bf(fmaxf(acc[pxt][cot][1] + bb.y, 0.f)) << 16);
            unsigned int p1 = (unsigned int)f2bf(fmaxf(acc[pxt][cot][2] + bb.z, 0.f)) |
                              ((unsigned int)f2bf(fmaxf(acc[pxt][cot][3] + bb.w, 0.f)) << 16);
            *(uint2*)(orow + cb) = make_uint2(p0, p1);
        }
    }
}

// ---------- K10: MFMA gemm2: out[n,co,l] = relu(hb[n,l,:]·t2wb[co,:] + t2b[co]) ----------
__global__ __launch_bounds__(256) void k_gemm2(
    const unsigned short* __restrict__ hb, const unsigned short* __restrict__ wb,
    const float* __restrict__ t2b, float* __restrict__ out)
{
    int bid = blockIdx.x;                       // 1024
    int co_b = bid & 1, px_b = (bid >> 1) & 31, n = bid >> 6;
    int wv = threadIdx.x >> 6, lane = threadIdx.x & 63;
    int r = lane & 15, quad = lane >> 4;
    int px0 = (px_b << 7) + ((wv >> 1) << 6);
    int co0 = (co_b << 7) + ((wv & 1) << 6);
    const unsigned short* xrow = hb + ((size_t)n * L_ + px0) * C_;
    f32x4 acc[4][4];
#pragma unroll
    for (int i = 0; i < 4; ++i)
#pragma unroll
        for (int j = 0; j < 4; ++j) acc[i][j] = (f32x4){0.f, 0.f, 0.f, 0.f};
#pragma unroll 2
    for (int c0 = 0; c0 < 256; c0 += 32) {
        short8 A[4], B[4];
#pragma unroll
        for (int t = 0; t < 4; ++t)
            A[t] = *(const short8*)(wb + (size_t)(co0 + (t << 4) + r) * C_ + c0 + (quad << 3));
#pragma unroll
        for (int t = 0; t < 4; ++t)
            B[t] = *(const short8*)(xrow + (size_t)((t << 4) + r) * C_ + c0 + (quad << 3));
#pragma unroll
        for (int pxt = 0; pxt < 4; ++pxt)
#pragma unroll
            for (int cot = 0; cot < 4; ++cot)
                acc[pxt][cot] = __builtin_amdgcn_mfma_f32_16x16x32_bf16(A[cot], B[pxt], acc[pxt][cot], 0, 0, 0);
    }
#pragma unroll
    for (int pxt = 0; pxt < 4; ++pxt) {
        int px = px0 + (pxt << 4) + r;
#pragma unroll
        for (int cot = 0; cot < 4; ++cot) {
            int cb = co0 + (cot << 4) + (quad << 2);
            float4 bb = *(const float4*)(t2b + cb);
            out[((size_t)n * C_ + cb + 0) * L_ + px] = fmaxf(acc[pxt][cot][0] + bb.x, 0.f);
            out[((size_t)n * C_ + cb + 1) * L_ + px] = fmaxf(acc[pxt][cot][1] + bb.y, 0.f);
            out[((size_t)n * C_ + cb + 2) * L_ + px] = fmaxf(acc[pxt][cot][2] + bb.z, 0.f);
            out[((size_t)n * C_ + cb + 3) * L_ + px] = fmaxf(acc[pxt][cot][3] + bb.w, 0.f);
        }
    }
}

extern "C" void kernel_launch(void* const* d_in, const int* in_sizes, int n_in,
                              void* d_out, int out_size, void* d_ws, size_t ws_size,
                              hipStream_t stream)
{
    const float* feature = (const float*)d_in[0];
    const float* conv_w  = (const float*)d_in[1];
    const float* conv_b  = (const float*)d_in[2];
    const float* cent    = (const float*)d_in[3];
    const float* upfc_w  = (const float*)d_in[4];
    const float* upfc_b  = (const float*)d_in[5];
    const float* t1w     = (const float*)d_in[6];
    const float* t1b     = (const float*)d_in[7];
    const float* t2w     = (const float*)d_in[8];
    const float* t2b     = (const float*)d_in[9];

    float* ws = (float*)d_ws;                    // 43.3 MB total
    unsigned short* xnb = (unsigned short*)ws;           // 16777216 us (32 MB)
    unsigned short* hb  = xnb;                           // alias: xnb dead after k_conv
    float* rest  = ws + 8388608;
    float* rinv  = rest;                         // 65536
    float* sa    = rinv + 65536;                 // 2097152 (8 MB)
    float* up    = sa + 2097152;                 // 131072
    float* upn   = up + 131072;                  // 131072
    float* ssum  = upn + 131072;                 // 512
    float* rowss = ssum + 512;                   // 512
    float* upvec = rowss + 512;                  // 4096
    float* t1up  = upvec + 4096;                 // 4096
    unsigned short* wbconv = (unsigned short*)upn;       // alias: upn written later by k_rowfix
    unsigned short* t1wb = (unsigned short*)sa;          // alias: sa dead after k_einsum
    unsigned short* t2wb = t1wb + 65536;
    float* out = (float*)d_out;

    hipMemsetAsync(up, 0, 131072 * sizeof(float), stream);
    k_prep     <<<2048, 256, 0, stream>>>(feature, rinv, xnb);
    k_wpack    <<<288,  256, 0, stream>>>(conv_w, wbconv);
    k_conv     <<<1024, 256, 0, stream>>>(xnb, wbconv, conv_b, sa);
    k_ssum     <<<512,  256, 0, stream>>>(sa, ssum);
    k_einsum   <<<512,  256, 0, stream>>>(feature, rinv, sa, up);
    k_rowfix   <<<512,  256, 0, stream>>>(up, ssum, cent, upn, rowss);
    k_wpack2   <<<256,  256, 0, stream>>>(t1w, 512, t1wb);
    k_wpack2   <<<256,  256, 0, stream>>>(t2w, 256, t2wb);
    k_fc       <<<256,  256, 0, stream>>>(upn, rowss, upfc_w, upfc_b, upvec);
    k_t1up     <<<256,  256, 0, stream>>>(upvec, t1w, t1b, t1up);
    k_gemm1    <<<1024, 256, 0, stream>>>(feature, t1wb, t1up, hb);
    k_gemm2    <<<1024, 256, 0, stream>>>(hb, t2wb, t2b, out);
}

// Round 6
// 356.036 us; speedup vs baseline: 4.9170x; 1.0128x over previous
//
#include <hip/hip_runtime.h>
#include <cstdint>

#define N_ 16
#define C_ 256
#define H_ 64
#define W_ 64
#define L_ 4096          // H*W
#define K_ 32
#define CL_ (C_*L_)      // 1048576
#define KL_ (K_*L_)      // 131072
#define KC_ (K_*C_)      // 8192

typedef __attribute__((ext_vector_type(8))) short short8;   // 8 bf16 (4 VGPRs)
typedef __attribute__((ext_vector_type(4))) float f32x4;    // MFMA C/D frag

__device__ __forceinline__ unsigned short f2bf(float x) {   // RNE fp32->bf16
    unsigned int u = __float_as_uint(x);
    u += 0x7fffu + ((u >> 16) & 1u);
    return (unsigned short)(u >> 16);
}
__device__ __forceinline__ unsigned int pack2(float a, float b) {
    return (unsigned int)f2bf(a) | ((unsigned int)f2bf(b) << 16);
}

// ---------- K1: fused rinv + xn(bf16) transposed to (n,l,c) ----------
__global__ __launch_bounds__(256) void k_prep(
    const float* __restrict__ f, float* __restrict__ rinv,
    unsigned short* __restrict__ xnb)
{
    __shared__ float tile[256 * 34];            // [c][l], stride 34 (conflict-free)
    __shared__ float ssred[8 * 33];
    __shared__ float rbuf[32];
    int bid = blockIdx.x;
    int n = bid >> 7;
    int l0 = (bid & 127) << 5;
    int tid = threadIdx.x;
    int l = tid & 31, cb = tid >> 5;            // cb 0..7
    const float* fp = f + (size_t)n * CL_ + l0 + l;
    float ss = 0.f;
#pragma unroll
    for (int i = 0; i < 32; ++i) {
        int c = (cb << 5) + i;
        float v = fp[(size_t)c * L_];
        tile[c * 34 + l] = v;
        ss = fmaf(v, v, ss);
    }
    ssred[cb * 33 + l] = ss;
    __syncthreads();
    if (tid < 32) {
        float s = 0.f;
#pragma unroll
        for (int j = 0; j < 8; ++j) s += ssred[j * 33 + tid];
        float ri = 1.0f / fmaxf(sqrtf(s), 1e-12f);
        rinv[n * L_ + l0 + tid] = ri;
        rbuf[tid] = ri;
    }
    __syncthreads();
    float ri = rbuf[l];
    unsigned short* op = xnb + ((size_t)n * L_ + l0 + l) * C_ + (cb << 5);
#pragma unroll
    for (int g = 0; g < 4; ++g) {
        unsigned int pk[4];
#pragma unroll
        for (int d = 0; d < 4; ++d) {
            int c = (cb << 5) + (g << 3) + (d << 1);
            pk[d] = pack2(tile[c * 34 + l] * ri, tile[(c + 1) * 34 + l] * ri);
        }
        *(uint4*)(op + (g << 3)) = make_uint4(pk[0], pk[1], pk[2], pk[3]);
    }
}

// ---------- K2: repack conv weights -> wb[t][k][c] bf16 ----------
__global__ __launch_bounds__(256) void k_wpack(const float* __restrict__ w, unsigned short* __restrict__ wb) {
    int i = blockIdx.x * 256 + threadIdx.x;     // 73728
    int t = i >> 13;
    int k = (i >> 8) & 31;
    int c = i & 255;
    wb[i] = f2bf(w[k * 2304 + c * 9 + t]);
}

// ---------- generic 256x256 weight pack (row stride in floats) ----------
__global__ __launch_bounds__(256) void k_wpack2(const float* __restrict__ w, int stride,
                                                unsigned short* __restrict__ wb) {
    int i = blockIdx.x * 256 + threadIdx.x;     // 65536
    int co = i >> 8, ci = i & 255;
    wb[i] = f2bf(w[(size_t)co * stride + ci]);
}

// ---------- K3: double-buffered, software-pipelined MFMA 3x3 conv + fused softmax ----------
// grid: 16 n x 64 rows = 1024 blocks x 256 threads; wave w owns px = w*16..w*16+15
// LDS px-stride padded to 40 ushorts (80 B): banks spread {0,20,8,28,16,4,24,12} -> 2-way (free)
__global__ __launch_bounds__(256, 4) void k_conv(
    const unsigned short* __restrict__ xnb, const unsigned short* __restrict__ wb,
    const float* __restrict__ bias, float* __restrict__ sa)
{
    __shared__ __align__(16) unsigned short lsB[2][3 * 66 * 40];   // 2 x 15840 B
    int bid = blockIdx.x;
    int n = bid >> 6, y = bid & 63;
    int tid = threadIdx.x;
    int wv = tid >> 6, lane = tid & 63;
    int r = lane & 15, quad = lane >> 4;
    int pxw = (wv << 4) + r;                    // this lane's output x
    const unsigned short* xb = xnb + (size_t)n * CL_;

    // staging plan: 3 rows x 66 px x 4 quads = 792 uint4 items, 3-4 per thread
    const unsigned short* sptr[4];
    int sidx[4];
    bool svalid[4];
    int scnt = (tid < 24) ? 4 : 3;
#pragma unroll
    for (int k = 0; k < 4; ++k) {
        int j = tid + (k << 8);
        int row = j / 264; if (row > 2) row = 2;
        int rem = j - row * 264;
        int px = rem >> 2, q = rem & 3;
        int yy = y + row - 1, xx = px - 1;
        bool ok = ((unsigned)yy < 64u) && ((unsigned)xx < 64u);
        int yc = ok ? yy : 0, xc = ok ? xx : 0;
        sptr[k] = xb + (((size_t)(yc << 6) + xc) << 8) + (q << 3);
        svalid[k] = ok;
        sidx[k] = (row * 66 + px) * 40 + (q << 3);
    }
    const uint4 z4 = make_uint4(0, 0, 0, 0);
    uint4 pre[4];
#pragma unroll
    for (int k = 0; k < 4; ++k)
        pre[k] = (k < scnt && svalid[k]) ? *(const uint4*)sptr[k] : z4;

    f32x4 acc0 = (f32x4){0.f, 0.f, 0.f, 0.f};
    f32x4 acc1 = (f32x4){0.f, 0.f, 0.f, 0.f};
    for (int i = 0; i < 8; ++i) {
        int c0 = i << 5;
        unsigned short* buf = lsB[i & 1];
#pragma unroll
        for (int k = 0; k < 4; ++k)
            if (k < scnt) *(uint4*)(buf + sidx[k]) = pre[k];
        __syncthreads();                        // single barrier/chunk (see proof in journal)
        if (i < 7) {
#pragma unroll
            for (int k = 0; k < 4; ++k)
                pre[k] = (k < scnt && svalid[k]) ? *(const uint4*)(sptr[k] + c0 + 32) : z4;
        }
        const unsigned short* wchunk = wb + c0 + (quad << 3);
#pragma unroll
        for (int t = 0; t < 9; ++t) {
            int dy = t / 3, dx = t % 3;
            short8 B  = *(const short8*)(buf + (dy * 66 + pxw + dx) * 40 + (quad << 3));
            short8 A0 = *(const short8*)(wchunk + t * 8192 + r * 256);
            short8 A1 = *(const short8*)(wchunk + t * 8192 + (16 + r) * 256);
            acc0 = __builtin_amdgcn_mfma_f32_16x16x32_bf16(A0, B, acc0, 0, 0, 0);
            acc1 = __builtin_amdgcn_mfma_f32_16x16x32_bf16(A1, B, acc1, 0, 0, 0);
        }
    }
    // bias + softmax over k (32 values per px: 4 quads x 8 regs)
    float4 b0 = *(const float4*)(bias + (quad << 2));
    float4 b1 = *(const float4*)(bias + 16 + (quad << 2));
    float v[8];
    v[0] = acc0[0] + b0.x; v[1] = acc0[1] + b0.y; v[2] = acc0[2] + b0.z; v[3] = acc0[3] + b0.w;
    v[4] = acc1[0] + b1.x; v[5] = acc1[1] + b1.y; v[6] = acc1[2] + b1.z; v[7] = acc1[3] + b1.w;
    float mx = v[0];
#pragma unroll
    for (int j = 1; j < 8; ++j) mx = fmaxf(mx, v[j]);
    mx = fmaxf(mx, __shfl_xor(mx, 16));
    mx = fmaxf(mx, __shfl_xor(mx, 32));
    float s = 0.f;
#pragma unroll
    for (int j = 0; j < 8; ++j) { v[j] = __expf(v[j] - mx); s += v[j]; }
    s += __shfl_xor(s, 16);
    s += __shfl_xor(s, 32);
    float rs = 1.0f / s;
    int l = (y << 6) + pxw;
    float* sp = sa + (size_t)n * KL_ + l;
#pragma unroll
    for (int j = 0; j < 4; ++j) {
        sp[(size_t)((quad << 2) + j) * L_] = v[j] * rs;
        sp[(size_t)(16 + (quad << 2) + j) * L_] = v[4 + j] * rs;
    }
}

// ---------- K4: ssum[n,k] = sum_l sa[n,k,l] ----------
__global__ __launch_bounds__(256) void k_ssum(const float* __restrict__ sa, float* __restrict__ ssum) {
    __shared__ float red[256];
    int bid = blockIdx.x;                       // n*K + k
    const float* sp = sa + (size_t)bid * L_;
    float s = 0.f;
    for (int m = 0; m < 16; ++m) s += sp[threadIdx.x + (m << 8)];
    red[threadIdx.x] = s; __syncthreads();
    for (int st = 128; st > 0; st >>= 1) {
        if (threadIdx.x < st) red[threadIdx.x] += red[threadIdx.x + st];
        __syncthreads();
    }
    if (threadIdx.x == 0) ssum[bid] = red[0];
}

// ---------- K5: up[n,k,c] += sum_l sa[n,k,l] * xn[n,c,l] ----------
__global__ __launch_bounds__(256) void k_einsum(
    const float* __restrict__ f, const float* __restrict__ rinv,
    const float* __restrict__ sa, float* __restrict__ up)
{
    __shared__ float xn_s[C_ * 33];
    __shared__ float sa_s[K_ * 32];
    int bid = blockIdx.x;                       // 512
    int n = bid >> 5;
    int l0 = (bid & 31) << 7;
    int tid = threadIdx.x;
    int kq = tid >> 5, cq = tid & 31;
    float acc[4][8];
#pragma unroll
    for (int i = 0; i < 4; ++i)
#pragma unroll
        for (int j = 0; j < 8; ++j) acc[i][j] = 0.f;

    for (int ch = 0; ch < 4; ++ch) {
        int lc = l0 + (ch << 5);
        __syncthreads();
        {
            int crow = tid >> 3, lq = (tid & 7) << 2;
#pragma unroll
            for (int p = 0; p < 8; ++p) {
                int c = (p << 5) + crow;
                float4 f4 = *(const float4*)(f + (size_t)n * CL_ + (size_t)c * L_ + lc + lq);
                float4 r4 = *(const float4*)(rinv + n * L_ + lc + lq);
                float* d = xn_s + c * 33 + lq;
                d[0] = f4.x * r4.x; d[1] = f4.y * r4.y; d[2] = f4.z * r4.z; d[3] = f4.w * r4.w;
            }
        }
        {
            int k = tid >> 3, lq = (tid & 7) << 2;
            float4 a4 = *(const float4*)(sa + (size_t)n * KL_ + (size_t)k * L_ + lc + lq);
            *(float4*)(sa_s + (k << 5) + lq) = a4;
        }
        __syncthreads();
#pragma unroll 4
        for (int l = 0; l < 32; ++l) {
            float sv[4], xv[8];
#pragma unroll
            for (int i = 0; i < 4; ++i) sv[i] = sa_s[((kq << 2) + i) * 32 + l];
#pragma unroll
            for (int j = 0; j < 8; ++j) xv[j] = xn_s[(cq + (j << 5)) * 33 + l];
#pragma unroll
            for (int i = 0; i < 4; ++i)
#pragma unroll
                for (int j = 0; j < 8; ++j) acc[i][j] = fmaf(sv[i], xv[j], acc[i][j]);
        }
    }
    float* upp = up + (size_t)n * KC_;
#pragma unroll
    for (int i = 0; i < 4; ++i)
#pragma unroll
        for (int j = 0; j < 8; ++j)
            atomicAdd(upp + ((kq << 2) + i) * C_ + cq + (j << 5), acc[i][j]);
}

// ---------- K6: subtract centroid term, l2norm rows, record row sumsq ----------
__global__ __launch_bounds__(256) void k_rowfix(
    const float* __restrict__ up, const float* __restrict__ ssum,
    const float* __restrict__ cent, float* __restrict__ upn, float* __restrict__ rowss)
{
    __shared__ float red[256];
    int bid = blockIdx.x;                       // n*K + k
    int k = bid & 31;
    float sv = ssum[bid];
    float v = up[(size_t)bid * C_ + threadIdx.x] - sv * cent[k * C_ + threadIdx.x];
    red[threadIdx.x] = v * v; __syncthreads();
    for (int st = 128; st > 0; st >>= 1) {
        if (threadIdx.x < st) red[threadIdx.x] += red[threadIdx.x + st];
        __syncthreads();
    }
    float ss = red[0];
    float ri = 1.0f / fmaxf(sqrtf(ss), 1e-12f);
    upn[(size_t)bid * C_ + threadIdx.x] = v * ri;
    if (threadIdx.x == 0) rowss[bid] = ss * ri * ri;
}

// ---------- K7: global l2norm + FC, one block per output channel c ----------
__global__ __launch_bounds__(256) void k_fc(
    const float* __restrict__ upn, const float* __restrict__ rowss,
    const float* __restrict__ w, const float* __restrict__ b,
    float* __restrict__ upvec)
{
    __shared__ float rnb[16];
    __shared__ float red[16][5];
    int c = blockIdx.x;                         // 256
    int tid = threadIdx.x;
    int wv = tid >> 6, lane = tid & 63;
    if (tid < 16) {
        float ts = 0.f;
#pragma unroll
        for (int k = 0; k < K_; ++k) ts += rowss[(tid << 5) + k];
        rnb[tid] = 1.0f / fmaxf(sqrtf(ts), 1e-12f);
    }
    float acc[16];
#pragma unroll
    for (int n = 0; n < 16; ++n) acc[n] = 0.f;
    const float* wr = w + (size_t)c * KC_;
#pragma unroll
    for (int g = 0; g < 8; ++g) {
        int kc = (g << 10) + (tid << 2);
        float4 w4 = *(const float4*)(wr + kc);
#pragma unroll
        for (int n = 0; n < 16; ++n) {
            float4 u4 = *(const float4*)(upn + n * KC_ + kc);
            acc[n] += w4.x * u4.x + w4.y * u4.y + w4.z * u4.z + w4.w * u4.w;
        }
    }
#pragma unroll
    for (int n = 0; n < 16; ++n) {
        float a = acc[n];
#pragma unroll
        for (int s = 1; s < 64; s <<= 1) a += __shfl_xor(a, s);
        if (lane == 0) red[n][wv] = a;
    }
    __syncthreads();
    if (tid < 16) {
        float v = red[tid][0] + red[tid][1] + red[tid][2] + red[tid][3];
        upvec[tid * C_ + c] = v * rnb[tid] + b[c];
    }
}

// ---------- K8: t1up[n,co] = t1_w[co,256:512] . upvec[n,:] + t1_b[co] ----------
__global__ __launch_bounds__(256) void k_t1up(
    const float* __restrict__ upvec, const float* __restrict__ t1w,
    const float* __restrict__ t1b, float* __restrict__ t1up)
{
    __shared__ float wld[256];
    int co = blockIdx.x;                        // 256
    int tid = threadIdx.x;
    wld[tid] = t1w[(size_t)co * 512 + 256 + tid];
    __syncthreads();
    int n = tid >> 4, s = tid & 15;
    float a = 0.f;
#pragma unroll
    for (int i = 0; i < 16; ++i)
        a += wld[s + (i << 4)] * upvec[n * C_ + s + (i << 4)];
#pragma unroll
    for (int st = 1; st < 16; st <<= 1) a += __shfl_xor(a, st);
    if (s == 0) t1up[n * C_ + co] = a + t1b[co];
}

// ---------- K9: MFMA gemm1, pipelined LDS-staged B from fp32 feature ----------
// hb[n,l,co] = bf16(relu(f[n,:,l]·t1wb[co,:] + t1up[n,co]))
__global__ __launch_bounds__(256) void k_gemm1(
    const float* __restrict__ f, const unsigned short* __restrict__ wb,
    const float* __restrict__ t1up, unsigned short* __restrict__ hb)
{
    __shared__ __align__(16) unsigned int lsB[2][128 * 20];     // px stride 20 uints (padded)
    int bid = blockIdx.x;                       // 1024 = n(16) x px_b(32) x co_b(2)
    int co_b = bid & 1, px_b = (bid >> 1) & 31, n = bid >> 6;
    int l0 = px_b << 7;
    int tid = threadIdx.x;
    int wv = tid >> 6, lane = tid & 63;
    int r = lane & 15, quad = lane >> 4;
    int pxl = (wv >> 1) << 6;                   // block-local px base for wave
    int co0 = (co_b << 7) + ((wv & 1) << 6);
    const float* fb_ = f + (size_t)n * CL_ + l0;
    int c2 = tid & 15, pxg = tid >> 4;          // item 0; item 1 = +256 -> pxg+16

    unsigned int pk[2][4];
#pragma unroll
    for (int k2 = 0; k2 < 2; ++k2) {
        const float* s0 = fb_ + (size_t)(c2 << 1) * L_ + ((pxg + (k2 << 4)) << 2);
        float4 a = *(const float4*)s0;
        float4 b = *(const float4*)(s0 + L_);
        pk[k2][0] = pack2(a.x, b.x); pk[k2][1] = pack2(a.y, b.y);
        pk[k2][2] = pack2(a.z, b.z); pk[k2][3] = pack2(a.w, b.w);
    }
    f32x4 acc[4][4];
#pragma unroll
    for (int i = 0; i < 4; ++i)
#pragma unroll
        for (int j = 0; j < 4; ++j) acc[i][j] = (f32x4){0.f, 0.f, 0.f, 0.f};

    for (int i = 0; i < 8; ++i) {
        int c0 = i << 5;
        unsigned int* buf = lsB[i & 1];
#pragma unroll
        for (int k2 = 0; k2 < 2; ++k2) {
            int base = (pxg + (k2 << 4)) * 80 + c2;     // 4 px * 20-uint stride
            buf[base]      = pk[k2][0];
            buf[base + 20] = pk[k2][1];
            buf[base + 40] = pk[k2][2];
            buf[base + 60] = pk[k2][3];
        }
        __syncthreads();
        if (i < 7) {
#pragma unroll
            for (int k2 = 0; k2 < 2; ++k2) {
                const float* s0 = fb_ + (size_t)(c0 + 32 + (c2 << 1)) * L_ + ((pxg + (k2 << 4)) << 2);
                float4 a = *(const float4*)s0;
                float4 b = *(const float4*)(s0 + L_);
                pk[k2][0] = pack2(a.x, b.x); pk[k2][1] = pack2(a.y, b.y);
                pk[k2][2] = pack2(a.z, b.z); pk[k2][3] = pack2(a.w, b.w);
            }
        }
        short8 A[4], B[4];
#pragma unroll
        for (int t = 0; t < 4; ++t)
            A[t] = *(const short8*)(wb + (size_t)(co0 + (t << 4) + r) * C_ + c0 + (quad << 3));
#pragma unroll
        for (int t = 0; t < 4; ++t)
            B[t] = *(const short8*)((const unsigned short*)buf + (pxl + (t << 4) + r) * 40 + (quad << 3));
#pragma unroll
        for (int pxt = 0; pxt < 4; ++pxt)
#pragma unroll
            for (int cot = 0; cot < 4; ++cot)
                acc[pxt][cot] = __builtin_amdgcn_mfma_f32_16x16x32_bf16(A[cot], B[pxt], acc[pxt][cot], 0, 0, 0);
    }
#pragma unroll
    for (int pxt = 0; pxt < 4; ++pxt) {
        int px = l0 + pxl + (pxt << 4) + r;
        unsigned short* orow = hb + ((size_t)n * L_ + px) * C_;
#pragma unroll
        for (int cot = 0; cot < 4; ++cot) {
            int cb = co0 + (cot << 4) + (quad << 2);
            float4 bb = *(const float4*)(t1up + n * C_ + cb);
            unsigned int p0 = pack2(fmaxf(acc[pxt][cot][0] + bb.x, 0.f),
                                    fmaxf(acc[pxt][cot][1] + bb.y, 0.f));
            unsigned int p1 = pack2(fmaxf(acc[pxt][cot][2] + bb.z, 0.f),
                                    fmaxf(acc[pxt][cot][3] + bb.w, 0.f));
            *(uint2*)(orow + cb) = make_uint2(p0, p1);
        }
    }
}

// ---------- K10: MFMA gemm2, pipelined LDS-staged B from hb ----------
// out[n,co,l] = relu(hb[n,l,:]·t2wb[co,:] + t2b[co])
__global__ __launch_bounds__(256) void k_gemm2(
    const unsigned short* __restrict__ hb, const unsigned short* __restrict__ wb,
    const float* __restrict__ t2b, float* __restrict__ out)
{
    __shared__ __align__(16) unsigned short lsB[2][128 * 40];   // px stride 40 ushorts (padded)
    int bid = blockIdx.x;                       // 1024
    int co_b = bid & 1, px_b = (bid >> 1) & 31, n = bid >> 6;
    int l0 = px_b << 7;
    int tid = threadIdx.x;
    int wv = tid >> 6, lane = tid & 63;
    int r = lane & 15, quad = lane >> 4;
    int pxl = (wv >> 1) << 6;
    int co0 = (co_b << 7) + ((wv & 1) << 6);
    const unsigned short* hrow = hb + ((size_t)n * L_ + l0) * C_;
    int q = tid & 3, pxs = tid >> 2;            // item 0: px = pxs; item 1: px = pxs+64

    uint4 pre[2];
#pragma unroll
    for (int k2 = 0; k2 < 2; ++k2)
        pre[k2] = *(const uint4*)(hrow + (size_t)(pxs + (k2 << 6)) * C_ + (q << 3));

    f32x4 acc[4][4];
#pragma unroll
    for (int i = 0; i < 4; ++i)
#pragma unroll
        for (int j = 0; j < 4; ++j) acc[i][j] = (f32x4){0.f, 0.f, 0.f, 0.f};

    for (int i = 0; i < 8; ++i) {
        int c0 = i << 5;
        unsigned short* buf = lsB[i & 1];
#pragma unroll
        for (int k2 = 0; k2 < 2; ++k2)
            *(uint4*)(buf + (pxs + (k2 << 6)) * 40 + (q << 3)) = pre[k2];
        __syncthreads();
        if (i < 7) {
#pragma unroll
            for (int k2 = 0; k2 < 2; ++k2)
                pre[k2] = *(const uint4*)(hrow + (size_t)(pxs + (k2 << 6)) * C_ + c0 + 32 + (q << 3));
        }
        short8 A[4], B[4];
#pragma unroll
        for (int t = 0; t < 4; ++t)
            A[t] = *(const short8*)(wb + (size_t)(co0 + (t << 4) + r) * C_ + c0 + (quad << 3));
#pragma unroll
        for (int t = 0; t < 4; ++t)
            B[t] = *(const short8*)(buf + (pxl + (t << 4) + r) * 40 + (quad << 3));
#pragma unroll
        for (int pxt = 0; pxt < 4; ++pxt)
#pragma unroll
            for (int cot = 0; cot < 4; ++cot)
                acc[pxt][cot] = __builtin_amdgcn_mfma_f32_16x16x32_bf16(A[cot], B[pxt], acc[pxt][cot], 0, 0, 0);
    }
#pragma unroll
    for (int pxt = 0; pxt < 4; ++pxt) {
        int px = l0 + pxl + (pxt << 4) + r;
#pragma unroll
        for (int cot = 0; cot < 4; ++cot) {
            int cb = co0 + (cot << 4) + (quad << 2);
            float4 bb = *(const float4*)(t2b + cb);
            out[((size_t)n * C_ + cb + 0) * L_ + px] = fmaxf(acc[pxt][cot][0] + bb.x, 0.f);
            out[((size_t)n * C_ + cb + 1) * L_ + px] = fmaxf(acc[pxt][cot][1] + bb.y, 0.f);
            out[((size_t)n * C_ + cb + 2) * L_ + px] = fmaxf(acc[pxt][cot][2] + bb.z, 0.f);
            out[((size_t)n * C_ + cb + 3) * L_ + px] = fmaxf(acc[pxt][cot][3] + bb.w, 0.f);
        }
    }
}

extern "C" void kernel_launch(void* const* d_in, const int* in_sizes, int n_in,
                              void* d_out, int out_size, void* d_ws, size_t ws_size,
                              hipStream_t stream)
{
    const float* feature = (const float*)d_in[0];
    const float* conv_w  = (const float*)d_in[1];
    const float* conv_b  = (const float*)d_in[2];
    const float* cent    = (const float*)d_in[3];
    const float* upfc_w  = (const float*)d_in[4];
    const float* upfc_b  = (const float*)d_in[5];
    const float* t1w     = (const float*)d_in[6];
    const float* t1b     = (const float*)d_in[7];
    const float* t2w     = (const float*)d_in[8];
    const float* t2b     = (const float*)d_in[9];

    float* ws = (float*)d_ws;                    // 43.3 MB total
    unsigned short* xnb = (unsigned short*)ws;           // 16777216 us (32 MB)
    unsigned short* hb  = xnb;                           // alias: xnb dead after k_conv
    float* rest  = ws + 8388608;
    float* rinv  = rest;                         // 65536
    float* sa    = rinv + 65536;                 // 2097152 (8 MB)
    float* up    = sa + 2097152;                 // 131072
    float* upn   = up + 131072;                  // 131072
    float* ssum  = upn + 131072;                 // 512
    float* rowss = ssum + 512;                   // 512
    float* upvec = rowss + 512;                  // 4096
    float* t1up  = upvec + 4096;                 // 4096
    unsigned short* wbconv = (unsigned short*)upn;       // alias: upn written later by k_rowfix
    unsigned short* t1wb = (unsigned short*)sa;          // alias: sa dead after k_einsum
    unsigned short* t2wb = t1wb + 65536;
    float* out = (float*)d_out;

    hipMemsetAsync(up, 0, 131072 * sizeof(float), stream);
    k_prep     <<<2048, 256, 0, stream>>>(feature, rinv, xnb);
    k_wpack    <<<288,  256, 0, stream>>>(conv_w, wbconv);
    k_conv     <<<1024, 256, 0, stream>>>(xnb, wbconv, conv_b, sa);
    k_ssum     <<<512,  256, 0, stream>>>(sa, ssum);
    k_einsum   <<<512,  256, 0, stream>>>(feature, rinv, sa, up);
    k_rowfix   <<<512,  256, 0, stream>>>(up, ssum, cent, upn, rowss);
    k_wpack2   <<<256,  256, 0, stream>>>(t1w, 512, t1wb);
    k_wpack2   <<<256,  256, 0, stream>>>(t2w, 256, t2wb);
    k_fc       <<<256,  256, 0, stream>>>(upn, rowss, upfc_w, upfc_b, upvec);
    k_t1up     <<<256,  256, 0, stream>>>(upvec, t1w, t1b, t1up);
    k_gemm1    <<<1024, 256, 0, stream>>>(feature, t1wb, t1up, hb);
    k_gemm2    <<<1024, 256, 0, stream>>>(hb, t2wb, t2b, out);
}